// Round 6
// baseline (34389.090 us; speedup 1.0000x reference)
//
#include <hip/hip_runtime.h>
#include <cmath>

#define NB   32
#define TE   128
#define TD   32
#define VOC  32000
#define EMB  256
#define HH   512
#define CTXD 1024
#define DCW  1536   // dcat row: [ctx 1024 | h 512]
#define XCH  4      // scan xpre chunk (steps)

// ws float offsets. ints: cnt_d0 @0, cnt_d1 @64, dec cnt @128 (monotonic counters)
#define OHS  1024                        // harr [2][129][NB][HH]
#define OEO  (OHS + 2*129*NB*HH)         // enc_out [NB][TE][CTXD]
#define OEP  (OEO + NB*TE*CTXD)          // epre [NB][TE][8]
#define ODC  (OEP + NB*TE*8)             // dcat [TD+1][NB][DCW]
#define WSEND (ODC + (TD+1)*NB*DCW)      // ~40.3MB

__device__ __forceinline__ float sigf(float x) { return 1.0f / (1.0f + expf(-x)); }
__device__ __forceinline__ float hsum4(float4 v) { return (v.x + v.y) + (v.z + v.w); }

__device__ __forceinline__ void stg1(float* p, float v) {
  __hip_atomic_store(p, v, __ATOMIC_RELAXED, __HIP_MEMORY_SCOPE_AGENT);
}

__device__ __forceinline__ void fma4(float4& a, const float4 w, const float4 u) {
  a.x = fmaf(w.x, u.x, a.x); a.y = fmaf(w.y, u.y, a.y);
  a.z = fmaf(w.z, u.z, a.z); a.w = fmaf(w.w, u.w, a.w);
}

// Monotonic single-line barrier, all-relaxed (agent-acquire = buffer_inv sc1 =
// L2 nuke, R2 regression). __syncthreads drains vmcnt (sc1 stores at L3) before
// arrival RMW; cross-block data is read at per-step-fresh addresses only.
__device__ __forceinline__ void gbarM(int* cnt, int target) {
  __syncthreads();
  if (threadIdx.x == 0) {
    int v = __hip_atomic_fetch_add(cnt, 1, __ATOMIC_RELAXED, __HIP_MEMORY_SCOPE_AGENT);
    if (v != target - 1) {
      int it = 0;
      while (__hip_atomic_load(cnt, __ATOMIC_RELAXED, __HIP_MEMORY_SCOPE_AGENT) < target) {
        __builtin_amdgcn_s_sleep(1);
        if (++it > (1 << 20)) break;  // safety bail: garbage beats hang
      }
    }
  }
  __syncthreads();
}

// ---------------- BiLSTM scan: 64 blocks x 1024 thr, persistent ----------------
// dir = bid>>5 (independent 32-block halves, own counter). Block ob: 16 h-columns
// j0=ob*16 (64 gate-rows r=g*16+jj). Wave w (16): rows 4w..4w+3. lane = bq*16+kl.
// Whh register-resident: W[4][8] float4/thread. xpre (x@Wih+bias) per 4-step
// chunk in LDS -> critical path = h@Whh only. Barrier participants: 32.
__global__ void __launch_bounds__(1024)
scan_kernel(const int* __restrict__ enc_in, const int* __restrict__ lens,
            const float* __restrict__ emb_src,
            const float* __restrict__ Wih_f, const float* __restrict__ Whh_f,
            const float* __restrict__ bih_f, const float* __restrict__ bhh_f,
            const float* __restrict__ Wih_b, const float* __restrict__ Whh_b,
            const float* __restrict__ bih_b, const float* __restrict__ bhh_b,
            float* __restrict__ ws)
{
  const int tid = threadIdx.x, bid = blockIdx.x;
  const int dir = bid >> 5, ob = bid & 31;
  int* cnt = (int*)ws + dir * 64;
  float* harr = ws + OHS;
  float* eo   = ws + OEO;

  asm volatile("buffer_inv sc1" ::: "memory");  // purge stale clean lines (graph replays)

  __shared__ int   tokL[TE * NB];            // 16 KB
  __shared__ float xpre[XCH][NB][64];        // 32 KB  [ss][b][row]
  __shared__ float lds_g[64][33];            // 8.4 KB

  for (int i = tid; i < TE * NB; i += 1024) {
    int b = i & 31, s = i >> 5;
    int t = s;
    if (dir) { int L = lens[b]; t = (s < L) ? (L - 1 - s) : s; }
    tokL[i] = enc_in[b * TE + t];
  }
  if (tid < 512) {
    int b = tid >> 4, jj = tid & 15;
    stg1(&harr[((size_t)(dir * 129) * NB + b) * HH + ob * 16 + jj], 0.0f);
  }

  const int lane = tid & 63, w = tid >> 6;
  const int bq = lane >> 4, kl = lane & 15;
  const int j0 = ob * 16;
  const float* Wih = dir ? Wih_b : Wih_f;
  const float* Whh = dir ? Whh_b : Whh_f;
  const float* bih = dir ? bih_b : bih_f;
  const float* bhh = dir ? bhh_b : bhh_f;

  // register weights: rows r = 4w+ri, global o = (r>>4)*HH + j0 + (r&15)
  float4 W[4][8];
  #pragma unroll
  for (int ri = 0; ri < 4; ++ri) {
    const int r = 4 * w + ri;
    const int o = (r >> 4) * HH + j0 + (r & 15);
    #pragma unroll
    for (int c = 0; c < 8; ++c)
      W[ri][c] = *(const float4*)&Whh[(size_t)o * HH + c * 64 + kl * 4];
  }

  // xpre role: thread = (xb batch 0..31, xr2 row 0..31) -> rows xr2, xr2+32
  const int xb = tid >> 5, xr2 = tid & 31;
  const int o_x0 = (xr2 >> 4) * HH + j0 + (xr2 & 15);
  const int o_x1 = ((xr2 + 32) >> 4) * HH + j0 + ((xr2 + 32) & 15);
  const float4* xW0 = (const float4*)(Wih + (size_t)o_x0 * EMB);
  const float4* xW1 = (const float4*)(Wih + (size_t)o_x1 * EMB);
  const float bx0 = bih[o_x0] + bhh[o_x0];
  const float bx1 = bih[o_x1] + bhh[o_x1];

  // updater role (tid<512): (b_u, jj_u); c-state in register
  const int b_u = tid >> 4, jj_u = tid & 15;
  const int j_u = j0 + jj_u;
  const int Lu = (tid < 512) ? lens[b_u] : 0;
  float cst = 0.0f;

  int tgt = 32;
  gbarM(cnt, tgt); tgt += 32;     // h0 visible grid-wide

  for (int s = 0; s < TE; ++s) {
    if ((s & (XCH - 1)) == 0) {
      for (int ss = 0; ss < XCH; ++ss) {
        int tok = tokL[(s + ss) * 32 + xb];
        const float4* x4 = (const float4*)(emb_src + (size_t)tok * EMB);
        float4 p0a = {0,0,0,0}, p0b = {0,0,0,0}, p1a = {0,0,0,0}, p1b = {0,0,0,0};
        #pragma unroll 8
        for (int k = 0; k < 64; k += 2) {
          float4 xa = x4[k], xb4 = x4[k + 1];
          fma4(p0a, xW0[k], xa); fma4(p0b, xW0[k + 1], xb4);
          fma4(p1a, xW1[k], xa); fma4(p1b, xW1[k + 1], xb4);
        }
        xpre[ss][xb][xr2]      = hsum4(p0a) + hsum4(p0b) + bx0;
        xpre[ss][xb][xr2 + 32] = hsum4(p1a) + hsum4(p1b) + bx1;
      }
      __syncthreads();
    }

    const float* hbase = harr + ((size_t)(dir * 129 + s) * NB) * HH;
    #pragma unroll
    for (int half = 0; half < 2; ++half) {
      float4 a[4][4] = {};       // [ri][bg]
      #pragma unroll
      for (int c = 0; c < 8; ++c) {
        float4 u[4];
        #pragma unroll
        for (int bg = 0; bg < 4; ++bg) {
          int b = (half * 4 + bg) * 4 + bq;
          u[bg] = *(const float4*)&hbase[(size_t)b * HH + c * 64 + kl * 4];
        }
        #pragma unroll
        for (int ri = 0; ri < 4; ++ri)
          #pragma unroll
          for (int bg = 0; bg < 4; ++bg)
            fma4(a[ri][bg], W[ri][c], u[bg]);
      }
      #pragma unroll
      for (int ri = 0; ri < 4; ++ri)
        #pragma unroll
        for (int bg = 0; bg < 4; ++bg) {
          int b = (half * 4 + bg) * 4 + bq;
          float sv = hsum4(a[ri][bg]);
          sv += __shfl_xor(sv, 1); sv += __shfl_xor(sv, 2);
          sv += __shfl_xor(sv, 4); sv += __shfl_xor(sv, 8);
          if (kl == 0) lds_g[4 * w + ri][b] = sv;
        }
    }
    __syncthreads();

    if (tid < 512) {
      const float* xp = &xpre[s & (XCH - 1)][b_u][0];
      float gi = xp[0  + jj_u] + lds_g[0  + jj_u][b_u];
      float gf = xp[16 + jj_u] + lds_g[16 + jj_u][b_u];
      float gg = xp[32 + jj_u] + lds_g[32 + jj_u][b_u];
      float go = xp[48 + jj_u] + lds_g[48 + jj_u][b_u];
      float c = sigf(gf) * cst + sigf(gi) * tanhf(gg);
      cst = c;
      float h = sigf(go) * tanhf(c);
      stg1(&harr[((size_t)(dir * 129 + s + 1) * NB + b_u) * HH + j_u], h);
      float hm = (s < Lu) ? h : 0.0f;
      int pos = dir ? ((s < Lu) ? (Lu - 1 - s) : s) : s;
      eo[((size_t)b_u * TE + pos) * CTXD + dir * HH + j_u] = hm;  // plain store
    }
    gbarM(cnt, tgt); tgt += 32;
  }
}

// ---------------- Decoder: 64 blocks x 512 thr, persistent ----------------
// P2: (pb=bid>>1, half=bid&1) attn scores+softmax (redundant per half) + 512-d
// ctx slice. P3: block owns 8 GRU columns j0=bid*8; wave w = column w (3 gate
// rows, 42 float4 weights in VGPRs); lane = bq*32 + kl(32). Barrier: 64-wide.
__global__ void __launch_bounds__(512)
dec_kernel(const int* __restrict__ dec_in, const int* __restrict__ lens,
           const float* __restrict__ emb_tgt,
           const float* __restrict__ gWih, const float* __restrict__ gWhh,
           const float* __restrict__ gbih, const float* __restrict__ gbhh,
           const float* __restrict__ attn_W, const float* __restrict__ attn_b,
           const float* __restrict__ attn_v,
           float* __restrict__ ws)
{
  const int tid = threadIdx.x, bid = blockIdx.x;
  int* cnt = (int*)ws + 128;
  float* eo   = ws + OEO;
  float* ep   = ws + OEP;
  float* dcat = ws + ODC;

  asm volatile("buffer_inv sc1" ::: "memory");

  __shared__ int tokD[TD * NB];
  __shared__ float av8[8];
  __shared__ float hpv[8];
  __shared__ float elds[128];
  __shared__ float wlds[128];
  __shared__ float redL[2];
  __shared__ float lds_d[2][8][3][32];

  for (int i = tid; i < TD * NB; i += 512) {
    int b = i & 31, s = i >> 5;
    tokD[i] = dec_in[b * TD + s];
  }
  if (tid < 8) av8[tid] = attn_v[tid];

  // pre-phase: ep = enc_out @ attn_W[:1024] + attn_b (all 64 blocks); h0 = 0
  {
    const int gt = bid * 512 + tid;          // 0..32767 = NB*TE*8 exactly
    {
      int a = gt & 7, t = (gt >> 3) & 127, b = gt >> 10;
      float acc = attn_b[a];
      const float* er = &eo[((size_t)b * TE + t) * CTXD];
      for (int d = 0; d < CTXD; d += 4) {
        float4 ev = *(const float4*)&er[d];
        acc = fmaf(ev.x, attn_W[(d + 0) * 8 + a], acc);
        acc = fmaf(ev.y, attn_W[(d + 1) * 8 + a], acc);
        acc = fmaf(ev.z, attn_W[(d + 2) * 8 + a], acc);
        acc = fmaf(ev.w, attn_W[(d + 3) * 8 + a], acc);
      }
      stg1(&ep[gt], acc);
    }
    if (gt < NB * HH) {
      int b = gt >> 9, j = gt & 511;
      stg1(&dcat[(size_t)b * DCW + CTXD + j], 0.0f);
    }
  }

  const int pb = bid >> 1, half = bid & 1;
  const int Lb = lens[pb];
  const int lane = tid & 63, w = tid >> 6;
  const int bq = lane >> 5, kl = lane & 31;
  const int j0 = bid * 8;

  // GRU register weights: wave w = column j0+w; rows g*HH + j0 + w, g=0..2
  // c 0..9: gWih k = c*128 (x 0..255 then ctx 256..1279); c 10..13: gWhh
  float4 WD0[14], WD1[14], WD2[14];
  {
    const int jc = j0 + w;
    const float* r0 = gWih + (size_t)(0 * HH + jc) * (EMB + CTXD);
    const float* r1 = gWih + (size_t)(1 * HH + jc) * (EMB + CTXD);
    const float* r2 = gWih + (size_t)(2 * HH + jc) * (EMB + CTXD);
    #pragma unroll
    for (int c = 0; c < 10; ++c) {
      WD0[c] = *(const float4*)&r0[c * 128 + kl * 4];
      WD1[c] = *(const float4*)&r1[c * 128 + kl * 4];
      WD2[c] = *(const float4*)&r2[c * 128 + kl * 4];
    }
    const float* h0 = gWhh + (size_t)(0 * HH + jc) * HH;
    const float* h1 = gWhh + (size_t)(1 * HH + jc) * HH;
    const float* h2 = gWhh + (size_t)(2 * HH + jc) * HH;
    #pragma unroll
    for (int c = 10; c < 14; ++c) {
      WD0[c] = *(const float4*)&h0[(c - 10) * 128 + kl * 4];
      WD1[c] = *(const float4*)&h1[(c - 10) * 128 + kl * 4];
      WD2[c] = *(const float4*)&h2[(c - 10) * 128 + kl * 4];
    }
  }

  // updater (tid<256): (b_u, jw_u); h-state in register
  const int b_u = tid & 31, jw_u = tid >> 5;
  const int j_u = j0 + jw_u;
  float bRi = 0, bRh = 0, bZi = 0, bZh = 0, bNi = 0, bNh = 0;
  if (tid < 256) {
    bRi = gbih[j_u];          bRh = gbhh[j_u];
    bZi = gbih[HH + j_u];     bZh = gbhh[HH + j_u];
    bNi = gbih[2 * HH + j_u]; bNh = gbhh[2 * HH + j_u];
  }
  float hreg = 0.0f;

  int tgt = 64;
  gbarM(cnt, tgt); tgt += 64;

  for (int s = 0; s < TD; ++s) {
    // ---- P2: scores (redundant per half), softmax, 512-d ctx slice ----
    const float* hrow = dcat + ((size_t)s * NB + pb) * DCW + CTXD;
    {
      float acc = 0.0f;
      const float4* h4 = (const float4*)hrow;
      float4 ha = h4[lane * 2], hb = h4[lane * 2 + 1];
      const float* wa = attn_W + (size_t)(CTXD + lane * 8) * 8 + w;
      acc = fmaf(ha.x, wa[0],  acc); acc = fmaf(ha.y, wa[8],  acc);
      acc = fmaf(ha.z, wa[16], acc); acc = fmaf(ha.w, wa[24], acc);
      acc = fmaf(hb.x, wa[32], acc); acc = fmaf(hb.y, wa[40], acc);
      acc = fmaf(hb.z, wa[48], acc); acc = fmaf(hb.w, wa[56], acc);
      acc += __shfl_xor(acc, 1);  acc += __shfl_xor(acc, 2);
      acc += __shfl_xor(acc, 4);  acc += __shfl_xor(acc, 8);
      acc += __shfl_xor(acc, 16); acc += __shfl_xor(acc, 32);
      if (lane == 0) hpv[w] = acc;
    }
    __syncthreads();
    if (tid < 128) {
      float evv = -1e9f;
      if (tid < Lb) {
        const float* e8 = &ep[((size_t)pb * TE + tid) * 8];
        float4 ea = *(const float4*)e8, eb2 = *(const float4*)(e8 + 4);
        evv  = tanhf(ea.x + hpv[0]) * av8[0];
        evv += tanhf(ea.y + hpv[1]) * av8[1];
        evv += tanhf(ea.z + hpv[2]) * av8[2];
        evv += tanhf(ea.w + hpv[3]) * av8[3];
        evv += tanhf(eb2.x + hpv[4]) * av8[4];
        evv += tanhf(eb2.y + hpv[5]) * av8[5];
        evv += tanhf(eb2.z + hpv[6]) * av8[6];
        evv += tanhf(eb2.w + hpv[7]) * av8[7];
      }
      elds[tid] = evv;
    }
    __syncthreads();
    if (tid < 64) {
      float m = fmaxf(elds[tid], elds[tid + 64]);
      m = fmaxf(m, __shfl_xor(m, 1));  m = fmaxf(m, __shfl_xor(m, 2));
      m = fmaxf(m, __shfl_xor(m, 4));  m = fmaxf(m, __shfl_xor(m, 8));
      m = fmaxf(m, __shfl_xor(m, 16)); m = fmaxf(m, __shfl_xor(m, 32));
      if (tid == 0) redL[0] = m;
    }
    __syncthreads();
    float mx = redL[0];
    if (tid < 128) wlds[tid] = expf(elds[tid] - mx);
    __syncthreads();
    if (tid < 64) {
      float sm = wlds[tid] + wlds[tid + 64];
      sm += __shfl_xor(sm, 1);  sm += __shfl_xor(sm, 2);
      sm += __shfl_xor(sm, 4);  sm += __shfl_xor(sm, 8);
      sm += __shfl_xor(sm, 16); sm += __shfl_xor(sm, 32);
      if (tid == 0) redL[1] = 1.0f / sm;
    }
    float cacc = 0.0f;
    {
      const int d = half * 512 + tid;
      const float* eb = eo + (size_t)pb * TE * CTXD + d;
      #pragma unroll 4
      for (int t = 0; t < TE; ++t)
        cacc = fmaf(wlds[t], eb[(size_t)t * CTXD], cacc);
    }
    __syncthreads();                      // redL[1] ready
    stg1(&dcat[((size_t)s * NB + pb) * DCW + half * 512 + tid], cacc * redL[1]);
    gbarM(cnt, tgt); tgt += 64;

    // ---- P3: GRU gate dots (all 8 waves) + update (tid<256) ----
    {
      #pragma unroll 2
      for (int bg = 0; bg < 16; ++bg) {
        int b = bg * 2 + bq;
        int tok = tokD[s * 32 + b];
        const float* xr_ = emb_tgt + (size_t)tok * EMB + kl * 4;
        const float* dr  = dcat + ((size_t)s * NB + b) * DCW;
        float4 ai0 = {0,0,0,0}, ai1 = {0,0,0,0}, ai2 = {0,0,0,0};
        float4 ah0 = {0,0,0,0}, ah1 = {0,0,0,0}, ah2 = {0,0,0,0};
        #pragma unroll
        for (int c = 0; c < 14; ++c) {
          float4 u;
          if (c < 2)       u = *(const float4*)&xr_[c * 128];
          else if (c < 10) u = *(const float4*)&dr[(c - 2) * 128 + 256 + kl * 4 - 256 + (c >= 2 ? 0 : 0)];
          else             u = *(const float4*)&dr[CTXD + (c - 10) * 128 + kl * 4];
          if (c >= 2 && c < 10) u = *(const float4*)&dr[(c - 2) * 128 + kl * 4];
          if (c < 10) { fma4(ai0, WD0[c], u); fma4(ai1, WD1[c], u); fma4(ai2, WD2[c], u); }
          else        { fma4(ah0, WD0[c], u); fma4(ah1, WD1[c], u); fma4(ah2, WD2[c], u); }
        }
        float s0 = hsum4(ai0), s1 = hsum4(ai1), s2 = hsum4(ai2);
        float t0 = hsum4(ah0), t1 = hsum4(ah1), t2 = hsum4(ah2);
        s0 += __shfl_xor(s0, 1);  t0 += __shfl_xor(t0, 1);
        s0 += __shfl_xor(s0, 2);  t0 += __shfl_xor(t0, 2);
        s0 += __shfl_xor(s0, 4);  t0 += __shfl_xor(t0, 4);
        s0 += __shfl_xor(s0, 8);  t0 += __shfl_xor(t0, 8);
        s0 += __shfl_xor(s0, 16); t0 += __shfl_xor(t0, 16);
        s1 += __shfl_xor(s1, 1);  t1 += __shfl_xor(t1, 1);
        s1 += __shfl_xor(s1, 2);  t1 += __shfl_xor(t1, 2);
        s1 += __shfl_xor(s1, 4);  t1 += __shfl_xor(t1, 4);
        s1 += __shfl_xor(s1, 8);  t1 += __shfl_xor(t1, 8);
        s1 += __shfl_xor(s1, 16); t1 += __shfl_xor(t1, 16);
        s2 += __shfl_xor(s2, 1);  t2 += __shfl_xor(t2, 1);
        s2 += __shfl_xor(s2, 2);  t2 += __shfl_xor(t2, 2);
        s2 += __shfl_xor(s2, 4);  t2 += __shfl_xor(t2, 4);
        s2 += __shfl_xor(s2, 8);  t2 += __shfl_xor(t2, 8);
        s2 += __shfl_xor(s2, 16); t2 += __shfl_xor(t2, 16);
        if (kl == 0) {
          lds_d[0][w][0][b] = s0; lds_d[1][w][0][b] = t0;
          lds_d[0][w][1][b] = s1; lds_d[1][w][1][b] = t1;
          lds_d[0][w][2][b] = s2; lds_d[1][w][2][b] = t2;
        }
      }
    }
    __syncthreads();
    if (tid < 256) {
      float giR = lds_d[0][jw_u][0][b_u], ghR = lds_d[1][jw_u][0][b_u];
      float giZ = lds_d[0][jw_u][1][b_u], ghZ = lds_d[1][jw_u][1][b_u];
      float giN = lds_d[0][jw_u][2][b_u], ghN = lds_d[1][jw_u][2][b_u];
      float r = sigf(giR + bRi + ghR + bRh);
      float z = sigf(giZ + bZi + ghZ + bZh);
      float n = tanhf(giN + bNi + r * (ghN + bNh));
      float hnew = (1.0f - z) * n + z * hreg;
      hreg = hnew;
      stg1(&dcat[((size_t)(s + 1) * NB + b_u) * DCW + CTXD + j_u], hnew);
    }
    gbarM(cnt, tgt); tgt += 64;
  }
}

// ---------------- Classifier: [1024,512] @ clf_W^T [512,32000], relu ----------------
__global__ void __launch_bounds__(256)
clf_kernel(const float* __restrict__ dcat, const float* __restrict__ W,
           const float* __restrict__ bias, float* __restrict__ out)
{
  asm volatile("buffer_inv sc1" ::: "memory");  // stale-clean-line insurance (replays)
  __shared__ __align__(16) float As[16][68];
  __shared__ __align__(16) float Bs[16][68];
  const int tid = threadIdx.x;
  const int tx = tid & 15, ty = tid >> 4;
  const int n0 = blockIdx.x * 64, m0 = blockIdx.y * 64;
  float acc[4][4] = {};
  const int lr = tid >> 2;
  const int lk = (tid & 3) * 4;
  const int r  = m0 + lr;                       // r = b*TD + t
  const float* arow = dcat + ((size_t)((r & 31) + 1) * NB + (r >> 5)) * DCW + CTXD;
  const float* brow = W + (size_t)(n0 + lr) * HH;

  for (int kc = 0; kc < HH; kc += 16) {
    float4 av = *(const float4*)&arow[kc + lk];
    float4 bv = *(const float4*)&brow[kc + lk];
    __syncthreads();
    As[lk + 0][lr] = av.x; As[lk + 1][lr] = av.y;
    As[lk + 2][lr] = av.z; As[lk + 3][lr] = av.w;
    Bs[lk + 0][lr] = bv.x; Bs[lk + 1][lr] = bv.y;
    Bs[lk + 2][lr] = bv.z; Bs[lk + 3][lr] = bv.w;
    __syncthreads();
    #pragma unroll
    for (int kk = 0; kk < 16; ++kk) {
      float4 a4 = *(const float4*)&As[kk][ty * 4];
      float4 b4 = *(const float4*)&Bs[kk][tx * 4];
      acc[0][0] = fmaf(a4.x, b4.x, acc[0][0]); acc[0][1] = fmaf(a4.x, b4.y, acc[0][1]);
      acc[0][2] = fmaf(a4.x, b4.z, acc[0][2]); acc[0][3] = fmaf(a4.x, b4.w, acc[0][3]);
      acc[1][0] = fmaf(a4.y, b4.x, acc[1][0]); acc[1][1] = fmaf(a4.y, b4.y, acc[1][1]);
      acc[1][2] = fmaf(a4.y, b4.z, acc[1][2]); acc[1][3] = fmaf(a4.y, b4.w, acc[1][3]);
      acc[2][0] = fmaf(a4.z, b4.x, acc[2][0]); acc[2][1] = fmaf(a4.z, b4.y, acc[2][1]);
      acc[2][2] = fmaf(a4.z, b4.z, acc[2][2]); acc[2][3] = fmaf(a4.z, b4.w, acc[2][3]);
      acc[3][0] = fmaf(a4.w, b4.x, acc[3][0]); acc[3][1] = fmaf(a4.w, b4.y, acc[3][1]);
      acc[3][2] = fmaf(a4.w, b4.z, acc[3][2]); acc[3][3] = fmaf(a4.w, b4.w, acc[3][3]);
    }
  }
  const int col = n0 + tx * 4;
  float4 bb4 = *(const float4*)&bias[col];
  #pragma unroll
  for (int i = 0; i < 4; ++i) {
    int row = m0 + ty * 4 + i;
    float4 o;
    o.x = fmaxf(acc[i][0] + bb4.x, 0.0f);
    o.y = fmaxf(acc[i][1] + bb4.y, 0.0f);
    o.z = fmaxf(acc[i][2] + bb4.z, 0.0f);
    o.w = fmaxf(acc[i][3] + bb4.w, 0.0f);
    *(float4*)&out[(size_t)row * VOC + col] = o;
  }
}

extern "C" void kernel_launch(void* const* d_in, const int* in_sizes, int n_in,
                              void* d_out, int out_size, void* d_ws, size_t ws_size,
                              hipStream_t stream)
{
  if (ws_size < (size_t)WSEND * 4) return;  // visible-failure guard

  const int* enc_in  = (const int*)d_in[0];
  const int* enc_len = (const int*)d_in[1];
  const int* dec_in  = (const int*)d_in[2];
  const float* emb_src = (const float*)d_in[4];
  const float* emb_tgt = (const float*)d_in[5];
  const float* Wih_f = (const float*)d_in[6];
  const float* Whh_f = (const float*)d_in[7];
  const float* bih_f = (const float*)d_in[8];
  const float* bhh_f = (const float*)d_in[9];
  const float* Wih_b = (const float*)d_in[10];
  const float* Whh_b = (const float*)d_in[11];
  const float* bih_b = (const float*)d_in[12];
  const float* bhh_b = (const float*)d_in[13];
  const float* gWih  = (const float*)d_in[14];
  const float* gWhh  = (const float*)d_in[15];
  const float* gbih  = (const float*)d_in[16];
  const float* gbhh  = (const float*)d_in[17];
  const float* attn_W = (const float*)d_in[18];
  const float* attn_b = (const float*)d_in[19];
  const float* attn_v = (const float*)d_in[20];
  const float* clf_W = (const float*)d_in[21];
  const float* clf_b = (const float*)d_in[22];
  float* ws  = (float*)d_ws;
  float* out = (float*)d_out;

  hipMemsetAsync(d_ws, 0, 4096, stream);  // monotonic counters
  scan_kernel<<<64, 1024, 0, stream>>>(enc_in, enc_len, emb_src,
      Wih_f, Whh_f, bih_f, bhh_f, Wih_b, Whh_b, bih_b, bhh_b, ws);
  dec_kernel<<<64, 512, 0, stream>>>(dec_in, enc_len, emb_tgt,
      gWih, gWhh, gbih, gbhh, attn_W, attn_b, attn_v, ws);
  dim3 cg(VOC / 64, (NB * TD) / 64);
  clf_kernel<<<cg, 256, 0, stream>>>(ws + ODC, clf_W, clf_b, out);
}

// Round 7
// 3321.698 us; speedup vs baseline: 10.3529x; 10.3529x over previous
//
#include <hip/hip_runtime.h>
#include <cmath>

#define NB   32
#define TE   128
#define TD   32
#define VOC  32000
#define EMB  256
#define HH   512
#define CTXD 1024
#define DCW  1536   // dcat row: [ctx 1024 | h 512]

// ws float offsets. ints: cnt_d0 @0, cnt_d1 @64, dec cnt @128 (monotonic counters)
#define OHS  1024                        // harr [2][129][NB][HH]
#define OEO  (OHS + 2*129*NB*HH)         // enc_out [NB][TE][CTXD]
#define OEP  (OEO + NB*TE*CTXD)          // epre [NB][TE][8]
#define ODC  (OEP + NB*TE*8)             // dcat [TD+1][NB][DCW]
#define WSEND (ODC + (TD+1)*NB*DCW)      // ~40.3MB

__device__ __forceinline__ float sigf(float x) { return 1.0f / (1.0f + expf(-x)); }
__device__ __forceinline__ float hsum4(float4 v) { return (v.x + v.y) + (v.z + v.w); }

__device__ __forceinline__ void stg1(float* p, float v) {
  __hip_atomic_store(p, v, __ATOMIC_RELAXED, __HIP_MEMORY_SCOPE_AGENT);
}

__device__ __forceinline__ void fma4(float4& a, const float4 w, const float4 u) {
  a.x = fmaf(w.x, u.x, a.x); a.y = fmaf(w.y, u.y, a.y);
  a.z = fmaf(w.z, u.z, a.z); a.w = fmaf(w.w, u.w, a.w);
}

// Monotonic single-line barrier, all-relaxed (agent-acquire = buffer_inv sc1 =
// L2 nuke, R2 regression). __syncthreads drains vmcnt (sc1 stores at L3) before
// arrival RMW; cross-block data is read at per-step-fresh addresses only.
__device__ __forceinline__ void gbarM(int* cnt, int target) {
  __syncthreads();
  if (threadIdx.x == 0) {
    int v = __hip_atomic_fetch_add(cnt, 1, __ATOMIC_RELAXED, __HIP_MEMORY_SCOPE_AGENT);
    if (v != target - 1) {
      int it = 0;
      while (__hip_atomic_load(cnt, __ATOMIC_RELAXED, __HIP_MEMORY_SCOPE_AGENT) < target) {
        __builtin_amdgcn_s_sleep(1);
        if (++it > (1 << 20)) break;  // safety bail: garbage beats hang
      }
    }
  }
  __syncthreads();
}

// ---------------- BiLSTM scan: 256 blocks x 512 thr, persistent ----------------
// dir = bid>>7 (independent 128-block halves, own counter). Block ob: 4 h-cols
// j0=ob*4 (16 gate rows r=g*4+jj). Wave w = (ks=w&3 k-slice of 192, rh=w>>2 rows
// rh*8..+7). lane = bq*16+kl. Weights Wreg[8][3] float4 = 96 VGPR, loaded once.
// u=[x|h] read from global EXACTLY ONCE per block per step (no wave redundancy).
__global__ void __launch_bounds__(512)
scan_kernel(const int* __restrict__ enc_in, const int* __restrict__ lens,
            const float* __restrict__ emb_src,
            const float* __restrict__ Wih_f, const float* __restrict__ Whh_f,
            const float* __restrict__ bih_f, const float* __restrict__ bhh_f,
            const float* __restrict__ Wih_b, const float* __restrict__ Whh_b,
            const float* __restrict__ bih_b, const float* __restrict__ bhh_b,
            float* __restrict__ ws)
{
  const int tid = threadIdx.x, bid = blockIdx.x;
  const int dir = bid >> 7, ob = bid & 127;
  int* cnt = (int*)ws + dir * 64;
  float* harr = ws + OHS;
  float* eo   = ws + OEO;

  asm volatile("buffer_inv sc1" ::: "memory");  // purge stale clean lines (graph replays)

  __shared__ int   tokL[TE * NB];            // 16 KB
  __shared__ float lds_p[NB][68];            // [b][ks*16+r], pad 68 -> bank spread

  for (int i = tid; i < TE * NB; i += 512) {
    int b = i & 31, s = i >> 5;
    int t = s;
    if (dir) { int L = lens[b]; t = (s < L) ? (L - 1 - s) : s; }
    tokL[i] = enc_in[b * TE + t];
  }
  if (tid < 128) {
    int b = tid >> 2, jj = tid & 3;
    stg1(&harr[((size_t)(dir * 129) * NB + b) * HH + ob * 4 + jj], 0.0f);
  }

  const int lane = tid & 63, w = tid >> 6;
  const int ks = w & 3, rh = w >> 2;
  const int bq = lane >> 4, kl = lane & 15;
  const int j0 = ob * 4;
  const float* Wih = dir ? Wih_b : Wih_f;
  const float* Whh = dir ? Whh_b : Whh_f;

  // weights once: rows r = rh*8+ri, k float4 index kf = (ks*3+p)*16+kl
  float4 Wreg[8][3];
  #pragma unroll
  for (int ri = 0; ri < 8; ++ri) {
    int r = rh * 8 + ri;
    int o = (r >> 2) * HH + j0 + (r & 3);
    #pragma unroll
    for (int p = 0; p < 3; ++p) {
      int kf = (ks * 3 + p) * 16 + kl;
      Wreg[ri][p] = (kf < 64)
        ? *((const float4*)Wih + (size_t)o * 64 + kf)
        : *((const float4*)Whh + (size_t)o * 128 + (kf - 64));
    }
  }

  // updater role (tid<128): (b_u, jj_u); c-state in register
  const int b_u = tid >> 2, jj_u = tid & 3;
  const int j_u = j0 + jj_u;
  const int Lu = (tid < 128) ? lens[b_u] : 0;
  float bs0 = 0, bs1 = 0, bs2 = 0, bs3 = 0;
  if (tid < 128) {
    const float* bih = dir ? bih_b : bih_f;
    const float* bhh = dir ? bhh_b : bhh_f;
    bs0 = bih[0 * HH + j_u] + bhh[0 * HH + j_u];
    bs1 = bih[1 * HH + j_u] + bhh[1 * HH + j_u];
    bs2 = bih[2 * HH + j_u] + bhh[2 * HH + j_u];
    bs3 = bih[3 * HH + j_u] + bhh[3 * HH + j_u];
  }
  float cst = 0.0f;

  int tgt = 128;
  gbarM(cnt, tgt); tgt += 128;   // h0 + tokL visible

  for (int s = 0; s < TE; ++s) {
    const float4* h4 = (const float4*)(harr + ((size_t)(dir * 129 + s) * NB) * HH);
    for (int bg = 0; bg < 8; ++bg) {
      const int b = bg * 4 + bq;
      const int tok = tokL[s * 32 + b];
      const float4* x4 = (const float4*)emb_src + (size_t)tok * 64;
      float4 u[3];
      #pragma unroll
      for (int p = 0; p < 3; ++p) {
        int c = ks * 3 + p;
        u[p] = (c < 4) ? x4[c * 16 + kl]
                       : h4[(size_t)b * 128 + (c - 4) * 16 + kl];
      }
      float sc[8];
      #pragma unroll
      for (int ri = 0; ri < 8; ++ri) {
        float4 a = {0, 0, 0, 0};
        fma4(a, Wreg[ri][0], u[0]);
        fma4(a, Wreg[ri][1], u[1]);
        fma4(a, Wreg[ri][2], u[2]);
        sc[ri] = hsum4(a);
      }
      #pragma unroll
      for (int ri = 0; ri < 8; ++ri) {
        sc[ri] += __shfl_xor(sc[ri], 1);
        sc[ri] += __shfl_xor(sc[ri], 2);
        sc[ri] += __shfl_xor(sc[ri], 4);
        sc[ri] += __shfl_xor(sc[ri], 8);
      }
      if (kl == 0) {
        float4 lo = {sc[0], sc[1], sc[2], sc[3]};
        float4 hi = {sc[4], sc[5], sc[6], sc[7]};
        *(float4*)&lds_p[b][ks * 16 + rh * 8]     = lo;
        *(float4*)&lds_p[b][ks * 16 + rh * 8 + 4] = hi;
      }
    }
    __syncthreads();

    if (tid < 128) {
      // gate g row index = g*4 + jj_u; sum over 4 k-slices
      float gi = bs0, gf = bs1, gg = bs2, go = bs3;
      #pragma unroll
      for (int k2 = 0; k2 < 4; ++k2) {
        gi += lds_p[b_u][k2 * 16 + 0  + jj_u];
        gf += lds_p[b_u][k2 * 16 + 4  + jj_u];
        gg += lds_p[b_u][k2 * 16 + 8  + jj_u];
        go += lds_p[b_u][k2 * 16 + 12 + jj_u];
      }
      float c = sigf(gf) * cst + sigf(gi) * tanhf(gg);
      cst = c;
      float h = sigf(go) * tanhf(c);
      stg1(&harr[((size_t)(dir * 129 + s + 1) * NB + b_u) * HH + j_u], h);
      float hm = (s < Lu) ? h : 0.0f;
      int pos = dir ? ((s < Lu) ? (Lu - 1 - s) : s) : s;
      eo[((size_t)b_u * TE + pos) * CTXD + dir * HH + j_u] = hm;  // plain store
    }
    gbarM(cnt, tgt); tgt += 128;
  }
}

// ---------------- Decoder: 256 blocks x 512 thr, persistent ----------------
// P2: (pb=bid>>3, ds=bid&7) attn scores+softmax (redundant per ds) + 128-d ctx.
// P3: block owns cols j = 2*bid, 2*bid+1. Wave w = (ks=w&3 k-slice of 448,
// jl=w>>2 column). WD[3][7] float4 = 84 VGPR. u=[x|ctx|h] read once per block.
// Separate i/h accumulators (GRU n-gate needs r*gh).
__global__ void __launch_bounds__(512)
dec_kernel(const int* __restrict__ dec_in, const int* __restrict__ lens,
           const float* __restrict__ emb_tgt,
           const float* __restrict__ gWih, const float* __restrict__ gWhh,
           const float* __restrict__ gbih, const float* __restrict__ gbhh,
           const float* __restrict__ attn_W, const float* __restrict__ attn_b,
           const float* __restrict__ attn_v,
           float* __restrict__ ws)
{
  const int tid = threadIdx.x, bid = blockIdx.x;
  int* cnt = (int*)ws + 128;
  float* eo   = ws + OEO;
  float* ep   = ws + OEP;
  float* dcat = ws + ODC;

  asm volatile("buffer_inv sc1" ::: "memory");

  __shared__ int tokD[TD * NB];
  __shared__ float av8[8];
  __shared__ float hpv[8];
  __shared__ float elds[128];
  __shared__ float wlds[128];
  __shared__ float redL[2];
  __shared__ float cpart[4][128];
  __shared__ float lds_pd[2][NB][36];   // [i/h][b][ks*9+r], pad 36 -> bank spread

  for (int i = tid; i < TD * NB; i += 512) {
    int b = i & 31, s = i >> 5;
    tokD[i] = dec_in[b * TD + s];
  }
  if (tid < 8) av8[tid] = attn_v[tid];

  // pre-phase: ep = enc_out @ attn_W[:1024] + attn_b ; h0 = 0
  {
    const int gt = bid * 512 + tid;
    if (gt < NB * TE * 8) {
      int a = gt & 7, t = (gt >> 3) & 127, b = gt >> 10;
      float acc = attn_b[a];
      const float* er = &eo[((size_t)b * TE + t) * CTXD];
      for (int d = 0; d < CTXD; d += 4) {
        float4 ev = *(const float4*)&er[d];
        acc = fmaf(ev.x, attn_W[(d + 0) * 8 + a], acc);
        acc = fmaf(ev.y, attn_W[(d + 1) * 8 + a], acc);
        acc = fmaf(ev.z, attn_W[(d + 2) * 8 + a], acc);
        acc = fmaf(ev.w, attn_W[(d + 3) * 8 + a], acc);
      }
      stg1(&ep[gt], acc);
    }
    if (gt < NB * HH) {
      int b = gt >> 9, j = gt & 511;
      stg1(&dcat[(size_t)b * DCW + CTXD + j], 0.0f);
    }
  }

  const int pb = bid >> 3, ds = bid & 7;
  const int Lb = lens[pb];
  const int lane = tid & 63, w = tid >> 6;
  const int ks = w & 3, jl = w >> 2;
  const int bq = lane >> 4, kl = lane & 15;

  // GRU weights once: col jc = 2*bid+jl; rows o = g*HH+jc; kf = (ks*7+p)*16+kl
  float4 WD[3][7];
  {
    const int jc = bid * 2 + jl;
    #pragma unroll
    for (int g = 0; g < 3; ++g) {
      int o = g * HH + jc;
      #pragma unroll
      for (int p = 0; p < 7; ++p) {
        int kf = (ks * 7 + p) * 16 + kl;
        WD[g][p] = (kf < 320)
          ? *((const float4*)gWih + (size_t)o * 320 + kf)
          : *((const float4*)gWhh + (size_t)o * 128 + (kf - 320));
      }
    }
  }

  // updater (tid<64): (b_u, jl_u), h-state in register
  const int b_u = tid & 31, jl_u = tid >> 5;
  const int j_u = bid * 2 + jl_u;
  float bRi = 0, bRh = 0, bZi = 0, bZh = 0, bNi = 0, bNh = 0;
  if (tid < 64) {
    bRi = gbih[j_u];          bRh = gbhh[j_u];
    bZi = gbih[HH + j_u];     bZh = gbhh[HH + j_u];
    bNi = gbih[2 * HH + j_u]; bNh = gbhh[2 * HH + j_u];
  }
  float hreg = 0.0f;

  int tgt = 256;
  gbarM(cnt, tgt); tgt += 256;

  for (int s = 0; s < TD; ++s) {
    // ---- P2: scores (redundant per ds), softmax, 128-d ctx slice ----
    const float* hrow = dcat + ((size_t)s * NB + pb) * DCW + CTXD;
    {
      float acc = 0.0f;
      const float4* h4 = (const float4*)hrow;
      float4 ha = h4[lane * 2], hb = h4[lane * 2 + 1];
      const float* wa = attn_W + (size_t)(CTXD + lane * 8) * 8 + w;
      acc = fmaf(ha.x, wa[0],  acc); acc = fmaf(ha.y, wa[8],  acc);
      acc = fmaf(ha.z, wa[16], acc); acc = fmaf(ha.w, wa[24], acc);
      acc = fmaf(hb.x, wa[32], acc); acc = fmaf(hb.y, wa[40], acc);
      acc = fmaf(hb.z, wa[48], acc); acc = fmaf(hb.w, wa[56], acc);
      acc += __shfl_xor(acc, 1);  acc += __shfl_xor(acc, 2);
      acc += __shfl_xor(acc, 4);  acc += __shfl_xor(acc, 8);
      acc += __shfl_xor(acc, 16); acc += __shfl_xor(acc, 32);
      if (lane == 0) hpv[w] = acc;
    }
    __syncthreads();
    if (tid < 128) {
      float evv = -1e9f;
      if (tid < Lb) {
        const float* e8 = &ep[((size_t)pb * TE + tid) * 8];
        float4 ea = *(const float4*)e8, eb2 = *(const float4*)(e8 + 4);
        evv  = tanhf(ea.x + hpv[0]) * av8[0];
        evv += tanhf(ea.y + hpv[1]) * av8[1];
        evv += tanhf(ea.z + hpv[2]) * av8[2];
        evv += tanhf(ea.w + hpv[3]) * av8[3];
        evv += tanhf(eb2.x + hpv[4]) * av8[4];
        evv += tanhf(eb2.y + hpv[5]) * av8[5];
        evv += tanhf(eb2.z + hpv[6]) * av8[6];
        evv += tanhf(eb2.w + hpv[7]) * av8[7];
      }
      elds[tid] = evv;
    }
    __syncthreads();
    if (tid < 64) {
      float m = fmaxf(elds[tid], elds[tid + 64]);
      m = fmaxf(m, __shfl_xor(m, 1));  m = fmaxf(m, __shfl_xor(m, 2));
      m = fmaxf(m, __shfl_xor(m, 4));  m = fmaxf(m, __shfl_xor(m, 8));
      m = fmaxf(m, __shfl_xor(m, 16)); m = fmaxf(m, __shfl_xor(m, 32));
      if (tid == 0) redL[0] = m;
    }
    __syncthreads();
    float mx = redL[0];
    if (tid < 128) wlds[tid] = expf(elds[tid] - mx);
    __syncthreads();
    if (tid < 64) {
      float sm = wlds[tid] + wlds[tid + 64];
      sm += __shfl_xor(sm, 1);  sm += __shfl_xor(sm, 2);
      sm += __shfl_xor(sm, 4);  sm += __shfl_xor(sm, 8);
      sm += __shfl_xor(sm, 16); sm += __shfl_xor(sm, 32);
      if (tid == 0) redL[1] = 1.0f / sm;
    }
    {
      const int d = tid & 127, tq = tid >> 7;
      float acc = 0.0f;
      const float* eb = eo + ((size_t)pb * TE + tq * 32) * CTXD + ds * 128 + d;
      #pragma unroll 4
      for (int t = 0; t < 32; ++t)
        acc = fmaf(wlds[tq * 32 + t], eb[(size_t)t * CTXD], acc);
      cpart[tq][d] = acc;
    }
    __syncthreads();
    if (tid < 128) {
      float c = (cpart[0][tid] + cpart[1][tid] + cpart[2][tid] + cpart[3][tid]) * redL[1];
      stg1(&dcat[((size_t)s * NB + pb) * DCW + ds * 128 + tid], c);
    }
    gbarM(cnt, tgt); tgt += 256;

    // ---- P3: k-split GRU dots (u read once per block) + update ----
    {
      const float4* d4base = (const float4*)dcat + (size_t)s * NB * (DCW / 4);
      for (int bg = 0; bg < 8; ++bg) {
        const int b = bg * 4 + bq;
        const int tok = tokD[s * 32 + b];
        const float4* x4 = (const float4*)emb_tgt + (size_t)tok * 64;
        const float4* d4 = d4base + (size_t)b * (DCW / 4);
        float4 ai[3] = {{0,0,0,0},{0,0,0,0},{0,0,0,0}};
        float4 ah[3] = {{0,0,0,0},{0,0,0,0},{0,0,0,0}};
        #pragma unroll
        for (int p = 0; p < 7; ++p) {
          int c = ks * 7 + p;
          float4 u = (c < 4) ? x4[c * 16 + kl] : d4[(c - 4) * 16 + kl];
          if (c < 20) {
            fma4(ai[0], WD[0][p], u); fma4(ai[1], WD[1][p], u); fma4(ai[2], WD[2][p], u);
          } else {
            fma4(ah[0], WD[0][p], u); fma4(ah[1], WD[1][p], u); fma4(ah[2], WD[2][p], u);
          }
        }
        float si[3], sh[3];
        #pragma unroll
        for (int g = 0; g < 3; ++g) { si[g] = hsum4(ai[g]); sh[g] = hsum4(ah[g]); }
        #pragma unroll
        for (int g = 0; g < 3; ++g) {
          si[g] += __shfl_xor(si[g], 1); sh[g] += __shfl_xor(sh[g], 1);
          si[g] += __shfl_xor(si[g], 2); sh[g] += __shfl_xor(sh[g], 2);
          si[g] += __shfl_xor(si[g], 4); sh[g] += __shfl_xor(sh[g], 4);
          si[g] += __shfl_xor(si[g], 8); sh[g] += __shfl_xor(sh[g], 8);
        }
        if (kl == 0) {
          #pragma unroll
          for (int g = 0; g < 3; ++g) {
            lds_pd[0][b][ks * 9 + jl * 3 + g] = si[g];
            lds_pd[1][b][ks * 9 + jl * 3 + g] = sh[g];
          }
        }
      }
    }
    __syncthreads();
    if (tid < 64) {
      float giR = 0, ghR = 0, giZ = 0, ghZ = 0, giN = 0, ghN = 0;
      #pragma unroll
      for (int k2 = 0; k2 < 4; ++k2) {
        giR += lds_pd[0][b_u][k2 * 9 + jl_u * 3 + 0];
        ghR += lds_pd[1][b_u][k2 * 9 + jl_u * 3 + 0];
        giZ += lds_pd[0][b_u][k2 * 9 + jl_u * 3 + 1];
        ghZ += lds_pd[1][b_u][k2 * 9 + jl_u * 3 + 1];
        giN += lds_pd[0][b_u][k2 * 9 + jl_u * 3 + 2];
        ghN += lds_pd[1][b_u][k2 * 9 + jl_u * 3 + 2];
      }
      float r = sigf(giR + bRi + ghR + bRh);
      float z = sigf(giZ + bZi + ghZ + bZh);
      float n = tanhf(giN + bNi + r * (ghN + bNh));
      float hnew = (1.0f - z) * n + z * hreg;
      hreg = hnew;
      stg1(&dcat[((size_t)(s + 1) * NB + b_u) * DCW + CTXD + j_u], hnew);
    }
    gbarM(cnt, tgt); tgt += 256;
  }
}

// ---------------- Classifier: [1024,512] @ clf_W^T [512,32000], relu ----------------
__global__ void __launch_bounds__(256)
clf_kernel(const float* __restrict__ dcat, const float* __restrict__ W,
           const float* __restrict__ bias, float* __restrict__ out)
{
  asm volatile("buffer_inv sc1" ::: "memory");  // stale-clean-line insurance (replays)
  __shared__ __align__(16) float As[16][68];
  __shared__ __align__(16) float Bs[16][68];
  const int tid = threadIdx.x;
  const int tx = tid & 15, ty = tid >> 4;
  const int n0 = blockIdx.x * 64, m0 = blockIdx.y * 64;
  float acc[4][4] = {};
  const int lr = tid >> 2;
  const int lk = (tid & 3) * 4;
  const int r  = m0 + lr;                       // r = b*TD + t
  const float* arow = dcat + ((size_t)((r & 31) + 1) * NB + (r >> 5)) * DCW + CTXD;
  const float* brow = W + (size_t)(n0 + lr) * HH;

  for (int kc = 0; kc < HH; kc += 16) {
    float4 av = *(const float4*)&arow[kc + lk];
    float4 bv = *(const float4*)&brow[kc + lk];
    __syncthreads();
    As[lk + 0][lr] = av.x; As[lk + 1][lr] = av.y;
    As[lk + 2][lr] = av.z; As[lk + 3][lr] = av.w;
    Bs[lk + 0][lr] = bv.x; Bs[lk + 1][lr] = bv.y;
    Bs[lk + 2][lr] = bv.z; Bs[lk + 3][lr] = bv.w;
    __syncthreads();
    #pragma unroll
    for (int kk = 0; kk < 16; ++kk) {
      float4 a4 = *(const float4*)&As[kk][ty * 4];
      float4 b4 = *(const float4*)&Bs[kk][tx * 4];
      acc[0][0] = fmaf(a4.x, b4.x, acc[0][0]); acc[0][1] = fmaf(a4.x, b4.y, acc[0][1]);
      acc[0][2] = fmaf(a4.x, b4.z, acc[0][2]); acc[0][3] = fmaf(a4.x, b4.w, acc[0][3]);
      acc[1][0] = fmaf(a4.y, b4.x, acc[1][0]); acc[1][1] = fmaf(a4.y, b4.y, acc[1][1]);
      acc[1][2] = fmaf(a4.y, b4.z, acc[1][2]); acc[1][3] = fmaf(a4.y, b4.w, acc[1][3]);
      acc[2][0] = fmaf(a4.z, b4.x, acc[2][0]); acc[2][1] = fmaf(a4.z, b4.y, acc[2][1]);
      acc[2][2] = fmaf(a4.z, b4.z, acc[2][2]); acc[2][3] = fmaf(a4.z, b4.w, acc[2][3]);
      acc[3][0] = fmaf(a4.w, b4.x, acc[3][0]); acc[3][1] = fmaf(a4.w, b4.y, acc[3][1]);
      acc[3][2] = fmaf(a4.w, b4.z, acc[3][2]); acc[3][3] = fmaf(a4.w, b4.w, acc[3][3]);
    }
  }
  const int col = n0 + tx * 4;
  float4 bb4 = *(const float4*)&bias[col];
  #pragma unroll
  for (int i = 0; i < 4; ++i) {
    int row = m0 + ty * 4 + i;
    float4 o;
    o.x = fmaxf(acc[i][0] + bb4.x, 0.0f);
    o.y = fmaxf(acc[i][1] + bb4.y, 0.0f);
    o.z = fmaxf(acc[i][2] + bb4.z, 0.0f);
    o.w = fmaxf(acc[i][3] + bb4.w, 0.0f);
    *(float4*)&out[(size_t)row * VOC + col] = o;
  }
}

extern "C" void kernel_launch(void* const* d_in, const int* in_sizes, int n_in,
                              void* d_out, int out_size, void* d_ws, size_t ws_size,
                              hipStream_t stream)
{
  if (ws_size < (size_t)WSEND * 4) return;  // visible-failure guard

  const int* enc_in  = (const int*)d_in[0];
  const int* enc_len = (const int*)d_in[1];
  const int* dec_in  = (const int*)d_in[2];
  const float* emb_src = (const float*)d_in[4];
  const float* emb_tgt = (const float*)d_in[5];
  const float* Wih_f = (const float*)d_in[6];
  const float* Whh_f = (const float*)d_in[7];
  const float* bih_f = (const float*)d_in[8];
  const float* bhh_f = (const float*)d_in[9];
  const float* Wih_b = (const float*)d_in[10];
  const float* Whh_b = (const float*)d_in[11];
  const float* bih_b = (const float*)d_in[12];
  const float* bhh_b = (const float*)d_in[13];
  const float* gWih  = (const float*)d_in[14];
  const float* gWhh  = (const float*)d_in[15];
  const float* gbih  = (const float*)d_in[16];
  const float* gbhh  = (const float*)d_in[17];
  const float* attn_W = (const float*)d_in[18];
  const float* attn_b = (const float*)d_in[19];
  const float* attn_v = (const float*)d_in[20];
  const float* clf_W = (const float*)d_in[21];
  const float* clf_b = (const float*)d_in[22];
  float* ws  = (float*)d_ws;
  float* out = (float*)d_out;

  hipMemsetAsync(d_ws, 0, 4096, stream);  // monotonic counters
  scan_kernel<<<256, 512, 0, stream>>>(enc_in, enc_len, emb_src,
      Wih_f, Whh_f, bih_f, bhh_f, Wih_b, Whh_b, bih_b, bhh_b, ws);
  dec_kernel<<<256, 512, 0, stream>>>(dec_in, enc_len, emb_tgt,
      gWih, gWhh, gbih, gbhh, attn_W, attn_b, attn_v, ws);
  dim3 cg(VOC / 64, (NB * TD) / 64);
  clf_kernel<<<cg, 256, 0, stream>>>(ws + ODC, clf_W, clf_b, out);
}

// Round 8
// 2681.885 us; speedup vs baseline: 12.8227x; 1.2386x over previous
//
#include <hip/hip_runtime.h>
#include <cmath>

#define NB   32
#define TE   128
#define TD   32
#define VOC  32000
#define EMB  256
#define HH   512
#define CTXD 1024
#define DCW  1536   // dcat row: [ctx 1024 | h 512]

// ws float offsets. ints 0..1023: barrier regions (16 lines x 16 ints each):
// scan d0 @0, scan d1 @256, dec @512
#define OHS  1024                        // harr [2][129][NB][HH]
#define OEO  (OHS + 2*129*NB*HH)         // enc_out [NB][TE][CTXD]
#define OEP  (OEO + NB*TE*CTXD)          // epre [NB][TE][8]
#define ODC  (OEP + NB*TE*8)             // dcat [TD+1][NB][DCW]
#define WSEND (ODC + (TD+1)*NB*DCW)      // ~40.3MB

__device__ __forceinline__ float sigf(float x) { return 1.0f / (1.0f + expf(-x)); }
__device__ __forceinline__ float hsum4(float4 v) { return (v.x + v.y) + (v.z + v.w); }

__device__ __forceinline__ void stg1(float* p, float v) {
  __hip_atomic_store(p, v, __ATOMIC_RELAXED, __HIP_MEMORY_SCOPE_AGENT);
}

__device__ __forceinline__ void fma4(float4& a, const float4 w, const float4 u) {
  a.x = fmaf(w.x, u.x, a.x); a.y = fmaf(w.y, u.y, a.y);
  a.z = fmaf(w.z, u.z, a.z); a.w = fmaf(w.w, u.w, a.w);
}

// Distributed-arrival monotonic barrier: arrivals spread over 16 cache lines
// (kills same-line RMW serialization, the ~11us/sync wall of R7); wave 0 polls
// the 16 line-counters in parallel and tree-sums. All-relaxed (agent-acquire =
// buffer_inv sc1 = L2 nuke, R2 regression). __syncthreads drains vmcnt (sc1
// stores at L3) before arrival; cross-block data read at per-step-fresh addrs.
__device__ __forceinline__ void gbarD(int* bar, int target) {
  __syncthreads();
  if (threadIdx.x == 0) {
    __hip_atomic_fetch_add(bar + (blockIdx.x & 15) * 16, 1,
                           __ATOMIC_RELAXED, __HIP_MEMORY_SCOPE_AGENT);
  }
  if (threadIdx.x < 64) {
    const int ln = threadIdx.x;
    int it = 0;
    while (true) {
      int v = 0;
      if (ln < 16)
        v = __hip_atomic_load(bar + ln * 16, __ATOMIC_RELAXED, __HIP_MEMORY_SCOPE_AGENT);
      v += __shfl_xor(v, 1); v += __shfl_xor(v, 2);
      v += __shfl_xor(v, 4); v += __shfl_xor(v, 8);
      v = __shfl(v, 0);
      if (v >= target) break;
      __builtin_amdgcn_s_sleep(1);
      if (++it > (1 << 20)) break;  // safety bail: garbage beats hang
    }
  }
  __syncthreads();
}

// ---------------- BiLSTM scan: 256 blocks x 512 thr, persistent ----------------
// dir = bid>>7 (independent 128-block halves, own region). Block ob: 4 h-cols
// j0=ob*4 (16 gate rows r=g*4+jj). Wave w = (ks=w&3 k-slice of 192, rh=w>>2 rows
// rh*8..+7). lane = bq*16+kl. Weights Wreg[8][3] float4 = 96 VGPR, loaded once.
// u=[x|h] read from global EXACTLY ONCE per block per step (no wave redundancy).
__global__ void __launch_bounds__(512)
scan_kernel(const int* __restrict__ enc_in, const int* __restrict__ lens,
            const float* __restrict__ emb_src,
            const float* __restrict__ Wih_f, const float* __restrict__ Whh_f,
            const float* __restrict__ bih_f, const float* __restrict__ bhh_f,
            const float* __restrict__ Wih_b, const float* __restrict__ Whh_b,
            const float* __restrict__ bih_b, const float* __restrict__ bhh_b,
            float* __restrict__ ws)
{
  const int tid = threadIdx.x, bid = blockIdx.x;
  const int dir = bid >> 7, ob = bid & 127;
  int* bar = (int*)ws + dir * 256;
  float* harr = ws + OHS;
  float* eo   = ws + OEO;

  asm volatile("buffer_inv sc1" ::: "memory");  // purge stale clean lines (graph replays)

  __shared__ int   tokL[TE * NB];            // 16 KB
  __shared__ float lds_p[NB][68];            // [b][ks*16+r], pad 68 -> bank spread

  for (int i = tid; i < TE * NB; i += 512) {
    int b = i & 31, s = i >> 5;
    int t = s;
    if (dir) { int L = lens[b]; t = (s < L) ? (L - 1 - s) : s; }
    tokL[i] = enc_in[b * TE + t];
  }
  if (tid < 128) {
    int b = tid >> 2, jj = tid & 3;
    stg1(&harr[((size_t)(dir * 129) * NB + b) * HH + ob * 4 + jj], 0.0f);
  }

  const int lane = tid & 63, w = tid >> 6;
  const int ks = w & 3, rh = w >> 2;
  const int bq = lane >> 4, kl = lane & 15;
  const int j0 = ob * 4;
  const float* Wih = dir ? Wih_b : Wih_f;
  const float* Whh = dir ? Whh_b : Whh_f;

  // weights once: rows r = rh*8+ri, k float4 index kf = (ks*3+p)*16+kl
  float4 Wreg[8][3];
  #pragma unroll
  for (int ri = 0; ri < 8; ++ri) {
    int r = rh * 8 + ri;
    int o = (r >> 2) * HH + j0 + (r & 3);
    #pragma unroll
    for (int p = 0; p < 3; ++p) {
      int kf = (ks * 3 + p) * 16 + kl;
      Wreg[ri][p] = (kf < 64)
        ? *((const float4*)Wih + (size_t)o * 64 + kf)
        : *((const float4*)Whh + (size_t)o * 128 + (kf - 64));
    }
  }

  // updater role (tid<128): (b_u, jj_u); c-state in register
  const int b_u = tid >> 2, jj_u = tid & 3;
  const int j_u = j0 + jj_u;
  const int Lu = (tid < 128) ? lens[b_u] : 0;
  float bs0 = 0, bs1 = 0, bs2 = 0, bs3 = 0;
  if (tid < 128) {
    const float* bih = dir ? bih_b : bih_f;
    const float* bhh = dir ? bhh_b : bhh_f;
    bs0 = bih[0 * HH + j_u] + bhh[0 * HH + j_u];
    bs1 = bih[1 * HH + j_u] + bhh[1 * HH + j_u];
    bs2 = bih[2 * HH + j_u] + bhh[2 * HH + j_u];
    bs3 = bih[3 * HH + j_u] + bhh[3 * HH + j_u];
  }
  float cst = 0.0f;

  int tgt = 128;
  gbarD(bar, tgt); tgt += 128;   // h0 + tokL visible

  for (int s = 0; s < TE; ++s) {
    const float4* h4 = (const float4*)(harr + ((size_t)(dir * 129 + s) * NB) * HH);
    for (int bg = 0; bg < 8; ++bg) {
      const int b = bg * 4 + bq;
      const int tok = tokL[s * 32 + b];
      const float4* x4 = (const float4*)emb_src + (size_t)tok * 64;
      float4 u[3];
      #pragma unroll
      for (int p = 0; p < 3; ++p) {
        int c = ks * 3 + p;
        u[p] = (c < 4) ? x4[c * 16 + kl]
                       : h4[(size_t)b * 128 + (c - 4) * 16 + kl];
      }
      float sc[8];
      #pragma unroll
      for (int ri = 0; ri < 8; ++ri) {
        float4 a = {0, 0, 0, 0};
        fma4(a, Wreg[ri][0], u[0]);
        fma4(a, Wreg[ri][1], u[1]);
        fma4(a, Wreg[ri][2], u[2]);
        sc[ri] = hsum4(a);
      }
      #pragma unroll
      for (int ri = 0; ri < 8; ++ri) {
        sc[ri] += __shfl_xor(sc[ri], 1);
        sc[ri] += __shfl_xor(sc[ri], 2);
        sc[ri] += __shfl_xor(sc[ri], 4);
        sc[ri] += __shfl_xor(sc[ri], 8);
      }
      if (kl == 0) {
        float4 lo = {sc[0], sc[1], sc[2], sc[3]};
        float4 hi = {sc[4], sc[5], sc[6], sc[7]};
        *(float4*)&lds_p[b][ks * 16 + rh * 8]     = lo;
        *(float4*)&lds_p[b][ks * 16 + rh * 8 + 4] = hi;
      }
    }
    __syncthreads();

    if (tid < 128) {
      float gi = bs0, gf = bs1, gg = bs2, go = bs3;
      #pragma unroll
      for (int k2 = 0; k2 < 4; ++k2) {
        gi += lds_p[b_u][k2 * 16 + 0  + jj_u];
        gf += lds_p[b_u][k2 * 16 + 4  + jj_u];
        gg += lds_p[b_u][k2 * 16 + 8  + jj_u];
        go += lds_p[b_u][k2 * 16 + 12 + jj_u];
      }
      float c = sigf(gf) * cst + sigf(gi) * tanhf(gg);
      cst = c;
      float h = sigf(go) * tanhf(c);
      stg1(&harr[((size_t)(dir * 129 + s + 1) * NB + b_u) * HH + j_u], h);
      float hm = (s < Lu) ? h : 0.0f;
      int pos = dir ? ((s < Lu) ? (Lu - 1 - s) : s) : s;
      eo[((size_t)b_u * TE + pos) * CTXD + dir * HH + j_u] = hm;  // plain store
    }
    gbarD(bar, tgt); tgt += 128;
  }
}

// ---------------- Decoder: 256 blocks x 512 thr, persistent ----------------
// P2: (pb=bid>>3, ds=bid&7) attn scores+softmax (redundant per ds) + 128-d ctx.
// P3: block owns cols j = 2*bid, 2*bid+1. Wave w = (ks=w&3 k-slice of 448,
// jl=w>>2 column). WD[3][7] float4 = 84 VGPR. u=[x|ctx|h] read once per block.
__global__ void __launch_bounds__(512)
dec_kernel(const int* __restrict__ dec_in, const int* __restrict__ lens,
           const float* __restrict__ emb_tgt,
           const float* __restrict__ gWih, const float* __restrict__ gWhh,
           const float* __restrict__ gbih, const float* __restrict__ gbhh,
           const float* __restrict__ attn_W, const float* __restrict__ attn_b,
           const float* __restrict__ attn_v,
           float* __restrict__ ws)
{
  const int tid = threadIdx.x, bid = blockIdx.x;
  int* bar = (int*)ws + 512;
  float* eo   = ws + OEO;
  float* ep   = ws + OEP;
  float* dcat = ws + ODC;

  asm volatile("buffer_inv sc1" ::: "memory");

  __shared__ int tokD[TD * NB];
  __shared__ float av8[8];
  __shared__ float hpv[8];
  __shared__ float elds[128];
  __shared__ float wlds[128];
  __shared__ float redL[2];
  __shared__ float cpart[4][128];
  __shared__ float lds_pd[2][NB][36];   // [i/h][b][ks*9+r]

  for (int i = tid; i < TD * NB; i += 512) {
    int b = i & 31, s = i >> 5;
    tokD[i] = dec_in[b * TD + s];
  }
  if (tid < 8) av8[tid] = attn_v[tid];

  // pre-phase: ep = enc_out @ attn_W[:1024] + attn_b ; h0 = 0
  {
    const int gt = bid * 512 + tid;
    if (gt < NB * TE * 8) {
      int a = gt & 7, t = (gt >> 3) & 127, b = gt >> 10;
      float acc = attn_b[a];
      const float* er = &eo[((size_t)b * TE + t) * CTXD];
      for (int d = 0; d < CTXD; d += 4) {
        float4 ev = *(const float4*)&er[d];
        acc = fmaf(ev.x, attn_W[(d + 0) * 8 + a], acc);
        acc = fmaf(ev.y, attn_W[(d + 1) * 8 + a], acc);
        acc = fmaf(ev.z, attn_W[(d + 2) * 8 + a], acc);
        acc = fmaf(ev.w, attn_W[(d + 3) * 8 + a], acc);
      }
      stg1(&ep[gt], acc);
    }
    if (gt < NB * HH) {
      int b = gt >> 9, j = gt & 511;
      stg1(&dcat[(size_t)b * DCW + CTXD + j], 0.0f);
    }
  }

  const int pb = bid >> 3, ds = bid & 7;
  const int Lb = lens[pb];
  const int lane = tid & 63, w = tid >> 6;
  const int ks = w & 3, jl = w >> 2;
  const int bq = lane >> 4, kl = lane & 15;

  // GRU weights once: col jc = 2*bid+jl; rows o = g*HH+jc; kf = (ks*7+p)*16+kl
  float4 WD[3][7];
  {
    const int jc = bid * 2 + jl;
    #pragma unroll
    for (int g = 0; g < 3; ++g) {
      int o = g * HH + jc;
      #pragma unroll
      for (int p = 0; p < 7; ++p) {
        int kf = (ks * 7 + p) * 16 + kl;
        WD[g][p] = (kf < 320)
          ? *((const float4*)gWih + (size_t)o * 320 + kf)
          : *((const float4*)gWhh + (size_t)o * 128 + (kf - 320));
      }
    }
  }

  // updater (tid<64): (b_u, jl_u), h-state in register
  const int b_u = tid & 31, jl_u = tid >> 5;
  const int j_u = bid * 2 + jl_u;
  float bRi = 0, bRh = 0, bZi = 0, bZh = 0, bNi = 0, bNh = 0;
  if (tid < 64) {
    bRi = gbih[j_u];          bRh = gbhh[j_u];
    bZi = gbih[HH + j_u];     bZh = gbhh[HH + j_u];
    bNi = gbih[2 * HH + j_u]; bNh = gbhh[2 * HH + j_u];
  }
  float hreg = 0.0f;

  int tgt = 256;
  gbarD(bar, tgt); tgt += 256;

  for (int s = 0; s < TD; ++s) {
    // ---- P2: scores (redundant per ds), softmax, 128-d ctx slice ----
    const float* hrow = dcat + ((size_t)s * NB + pb) * DCW + CTXD;
    {
      float acc = 0.0f;
      const float4* h4 = (const float4*)hrow;
      float4 ha = h4[lane * 2], hb = h4[lane * 2 + 1];
      const float* wa = attn_W + (size_t)(CTXD + lane * 8) * 8 + w;
      acc = fmaf(ha.x, wa[0],  acc); acc = fmaf(ha.y, wa[8],  acc);
      acc = fmaf(ha.z, wa[16], acc); acc = fmaf(ha.w, wa[24], acc);
      acc = fmaf(hb.x, wa[32], acc); acc = fmaf(hb.y, wa[40], acc);
      acc = fmaf(hb.z, wa[48], acc); acc = fmaf(hb.w, wa[56], acc);
      acc += __shfl_xor(acc, 1);  acc += __shfl_xor(acc, 2);
      acc += __shfl_xor(acc, 4);  acc += __shfl_xor(acc, 8);
      acc += __shfl_xor(acc, 16); acc += __shfl_xor(acc, 32);
      if (lane == 0) hpv[w] = acc;
    }
    __syncthreads();
    if (tid < 128) {
      float evv = -1e9f;
      if (tid < Lb) {
        const float* e8 = &ep[((size_t)pb * TE + tid) * 8];
        float4 ea = *(const float4*)e8, eb2 = *(const float4*)(e8 + 4);
        evv  = tanhf(ea.x + hpv[0]) * av8[0];
        evv += tanhf(ea.y + hpv[1]) * av8[1];
        evv += tanhf(ea.z + hpv[2]) * av8[2];
        evv += tanhf(ea.w + hpv[3]) * av8[3];
        evv += tanhf(eb2.x + hpv[4]) * av8[4];
        evv += tanhf(eb2.y + hpv[5]) * av8[5];
        evv += tanhf(eb2.z + hpv[6]) * av8[6];
        evv += tanhf(eb2.w + hpv[7]) * av8[7];
      }
      elds[tid] = evv;
    }
    __syncthreads();
    if (tid < 64) {
      float m = fmaxf(elds[tid], elds[tid + 64]);
      m = fmaxf(m, __shfl_xor(m, 1));  m = fmaxf(m, __shfl_xor(m, 2));
      m = fmaxf(m, __shfl_xor(m, 4));  m = fmaxf(m, __shfl_xor(m, 8));
      m = fmaxf(m, __shfl_xor(m, 16)); m = fmaxf(m, __shfl_xor(m, 32));
      if (tid == 0) redL[0] = m;
    }
    __syncthreads();
    float mx = redL[0];
    if (tid < 128) wlds[tid] = expf(elds[tid] - mx);
    __syncthreads();
    if (tid < 64) {
      float sm = wlds[tid] + wlds[tid + 64];
      sm += __shfl_xor(sm, 1);  sm += __shfl_xor(sm, 2);
      sm += __shfl_xor(sm, 4);  sm += __shfl_xor(sm, 8);
      sm += __shfl_xor(sm, 16); sm += __shfl_xor(sm, 32);
      if (tid == 0) redL[1] = 1.0f / sm;
    }
    {
      const int d = tid & 127, tq = tid >> 7;
      float acc = 0.0f;
      const float* eb = eo + ((size_t)pb * TE + tq * 32) * CTXD + ds * 128 + d;
      #pragma unroll 4
      for (int t = 0; t < 32; ++t)
        acc = fmaf(wlds[tq * 32 + t], eb[(size_t)t * CTXD], acc);
      cpart[tq][d] = acc;
    }
    __syncthreads();
    if (tid < 128) {
      float c = (cpart[0][tid] + cpart[1][tid] + cpart[2][tid] + cpart[3][tid]) * redL[1];
      stg1(&dcat[((size_t)s * NB + pb) * DCW + ds * 128 + tid], c);
    }
    gbarD(bar, tgt); tgt += 256;

    // ---- P3: k-split GRU dots (u read once per block) + update ----
    {
      const float4* d4base = (const float4*)dcat + (size_t)s * NB * (DCW / 4);
      for (int bg = 0; bg < 8; ++bg) {
        const int b = bg * 4 + bq;
        const int tok = tokD[s * 32 + b];
        const float4* x4 = (const float4*)emb_tgt + (size_t)tok * 64;
        const float4* d4 = d4base + (size_t)b * (DCW / 4);
        float4 ai[3] = {{0,0,0,0},{0,0,0,0},{0,0,0,0}};
        float4 ah[3] = {{0,0,0,0},{0,0,0,0},{0,0,0,0}};
        #pragma unroll
        for (int p = 0; p < 7; ++p) {
          int c = ks * 7 + p;
          float4 u = (c < 4) ? x4[c * 16 + kl] : d4[(c - 4) * 16 + kl];
          if (c < 20) {
            fma4(ai[0], WD[0][p], u); fma4(ai[1], WD[1][p], u); fma4(ai[2], WD[2][p], u);
          } else {
            fma4(ah[0], WD[0][p], u); fma4(ah[1], WD[1][p], u); fma4(ah[2], WD[2][p], u);
          }
        }
        float si[3], sh[3];
        #pragma unroll
        for (int g = 0; g < 3; ++g) { si[g] = hsum4(ai[g]); sh[g] = hsum4(ah[g]); }
        #pragma unroll
        for (int g = 0; g < 3; ++g) {
          si[g] += __shfl_xor(si[g], 1); sh[g] += __shfl_xor(sh[g], 1);
          si[g] += __shfl_xor(si[g], 2); sh[g] += __shfl_xor(sh[g], 2);
          si[g] += __shfl_xor(si[g], 4); sh[g] += __shfl_xor(sh[g], 4);
          si[g] += __shfl_xor(si[g], 8); sh[g] += __shfl_xor(sh[g], 8);
        }
        if (kl == 0) {
          #pragma unroll
          for (int g = 0; g < 3; ++g) {
            lds_pd[0][b][ks * 9 + jl * 3 + g] = si[g];
            lds_pd[1][b][ks * 9 + jl * 3 + g] = sh[g];
          }
        }
      }
    }
    __syncthreads();
    if (tid < 64) {
      float giR = 0, ghR = 0, giZ = 0, ghZ = 0, giN = 0, ghN = 0;
      #pragma unroll
      for (int k2 = 0; k2 < 4; ++k2) {
        giR += lds_pd[0][b_u][k2 * 9 + jl_u * 3 + 0];
        ghR += lds_pd[1][b_u][k2 * 9 + jl_u * 3 + 0];
        giZ += lds_pd[0][b_u][k2 * 9 + jl_u * 3 + 1];
        ghZ += lds_pd[1][b_u][k2 * 9 + jl_u * 3 + 1];
        giN += lds_pd[0][b_u][k2 * 9 + jl_u * 3 + 2];
        ghN += lds_pd[1][b_u][k2 * 9 + jl_u * 3 + 2];
      }
      float r = sigf(giR + bRi + ghR + bRh);
      float z = sigf(giZ + bZi + ghZ + bZh);
      float n = tanhf(giN + bNi + r * (ghN + bNh));
      float hnew = (1.0f - z) * n + z * hreg;
      hreg = hnew;
      stg1(&dcat[((size_t)(s + 1) * NB + b_u) * DCW + CTXD + j_u], hnew);
    }
    gbarD(bar, tgt); tgt += 256;
  }
}

// ---------------- Classifier: [1024,512] @ clf_W^T [512,32000], relu --------
// 128x128 tile, 256 thr, 8x8 acc/thread: halves L2/L3 traffic vs 64x64.
__global__ void __launch_bounds__(256)
clf_kernel(const float* __restrict__ dcat, const float* __restrict__ W,
           const float* __restrict__ bias, float* __restrict__ out)
{
  asm volatile("buffer_inv sc1" ::: "memory");  // stale-clean-line insurance (replays)
  __shared__ __align__(16) float As[16][132];
  __shared__ __align__(16) float Bs[16][132];
  const int tid = threadIdx.x;
  const int tx = tid & 15, ty = tid >> 4;
  const int n0 = blockIdx.x * 128, m0 = blockIdx.y * 128;
  float acc[8][8] = {};
  const int lr = tid >> 1;            // 0..127
  const int lk = (tid & 1) * 8;       // 0 or 8
  const int r  = m0 + lr;             // r = b*TD + t
  const float* arow = dcat + ((size_t)((r & 31) + 1) * NB + (r >> 5)) * DCW + CTXD;
  const float* brow = W + (size_t)(n0 + lr) * HH;

  for (int kc = 0; kc < HH; kc += 16) {
    float4 av0 = *(const float4*)&arow[kc + lk];
    float4 av1 = *(const float4*)&arow[kc + lk + 4];
    float4 bv0 = *(const float4*)&brow[kc + lk];
    float4 bv1 = *(const float4*)&brow[kc + lk + 4];
    __syncthreads();
    As[lk + 0][lr] = av0.x; As[lk + 1][lr] = av0.y;
    As[lk + 2][lr] = av0.z; As[lk + 3][lr] = av0.w;
    As[lk + 4][lr] = av1.x; As[lk + 5][lr] = av1.y;
    As[lk + 6][lr] = av1.z; As[lk + 7][lr] = av1.w;
    Bs[lk + 0][lr] = bv0.x; Bs[lk + 1][lr] = bv0.y;
    Bs[lk + 2][lr] = bv0.z; Bs[lk + 3][lr] = bv0.w;
    Bs[lk + 4][lr] = bv1.x; Bs[lk + 5][lr] = bv1.y;
    Bs[lk + 6][lr] = bv1.z; Bs[lk + 7][lr] = bv1.w;
    __syncthreads();
    #pragma unroll
    for (int kk = 0; kk < 16; ++kk) {
      float a8[8], b8[8];
      *(float4*)&a8[0] = *(const float4*)&As[kk][ty * 8];
      *(float4*)&a8[4] = *(const float4*)&As[kk][ty * 8 + 4];
      *(float4*)&b8[0] = *(const float4*)&Bs[kk][tx * 8];
      *(float4*)&b8[4] = *(const float4*)&Bs[kk][tx * 8 + 4];
      #pragma unroll
      for (int i = 0; i < 8; ++i)
        #pragma unroll
        for (int j = 0; j < 8; ++j)
          acc[i][j] = fmaf(a8[i], b8[j], acc[i][j]);
    }
  }
  const int col = n0 + tx * 8;
  float bb[8];
  *(float4*)&bb[0] = *(const float4*)&bias[col];
  *(float4*)&bb[4] = *(const float4*)&bias[col + 4];
  #pragma unroll
  for (int i = 0; i < 8; ++i) {
    int row = m0 + ty * 8 + i;
    float4 o0, o1;
    o0.x = fmaxf(acc[i][0] + bb[0], 0.0f); o0.y = fmaxf(acc[i][1] + bb[1], 0.0f);
    o0.z = fmaxf(acc[i][2] + bb[2], 0.0f); o0.w = fmaxf(acc[i][3] + bb[3], 0.0f);
    o1.x = fmaxf(acc[i][4] + bb[4], 0.0f); o1.y = fmaxf(acc[i][5] + bb[5], 0.0f);
    o1.z = fmaxf(acc[i][6] + bb[6], 0.0f); o1.w = fmaxf(acc[i][7] + bb[7], 0.0f);
    *(float4*)&out[(size_t)row * VOC + col]     = o0;
    *(float4*)&out[(size_t)row * VOC + col + 4] = o1;
  }
}

extern "C" void kernel_launch(void* const* d_in, const int* in_sizes, int n_in,
                              void* d_out, int out_size, void* d_ws, size_t ws_size,
                              hipStream_t stream)
{
  if (ws_size < (size_t)WSEND * 4) return;  // visible-failure guard

  const int* enc_in  = (const int*)d_in[0];
  const int* enc_len = (const int*)d_in[1];
  const int* dec_in  = (const int*)d_in[2];
  const float* emb_src = (const float*)d_in[4];
  const float* emb_tgt = (const float*)d_in[5];
  const float* Wih_f = (const float*)d_in[6];
  const float* Whh_f = (const float*)d_in[7];
  const float* bih_f = (const float*)d_in[8];
  const float* bhh_f = (const float*)d_in[9];
  const float* Wih_b = (const float*)d_in[10];
  const float* Whh_b = (const float*)d_in[11];
  const float* bih_b = (const float*)d_in[12];
  const float* bhh_b = (const float*)d_in[13];
  const float* gWih  = (const float*)d_in[14];
  const float* gWhh  = (const float*)d_in[15];
  const float* gbih  = (const float*)d_in[16];
  const float* gbhh  = (const float*)d_in[17];
  const float* attn_W = (const float*)d_in[18];
  const float* attn_b = (const float*)d_in[19];
  const float* attn_v = (const float*)d_in[20];
  const float* clf_W = (const float*)d_in[21];
  const float* clf_b = (const float*)d_in[22];
  float* ws  = (float*)d_ws;
  float* out = (float*)d_out;

  hipMemsetAsync(d_ws, 0, 4096, stream);  // barrier lines
  scan_kernel<<<256, 512, 0, stream>>>(enc_in, enc_len, emb_src,
      Wih_f, Whh_f, bih_f, bhh_f, Wih_b, Whh_b, bih_b, bhh_b, ws);
  dec_kernel<<<256, 512, 0, stream>>>(dec_in, enc_len, emb_tgt,
      gWih, gWhh, gbih, gbhh, attn_W, attn_b, attn_v, ws);
  dim3 cg(VOC / 128, (NB * TD) / 128);
  clf_kernel<<<cg, 256, 0, stream>>>(ws + ODC, clf_W, clf_b, out);
}

// Round 9
// 2637.540 us; speedup vs baseline: 13.0383x; 1.0168x over previous
//
#include <hip/hip_runtime.h>
#include <cmath>

#define NB   32
#define TE   128
#define TD   32
#define VOC  32000
#define EMB  256
#define HH   512
#define CTXD 1024
#define DCW  1536   // dcat row: [ctx 1024 | h 512]

// ws float offsets. ints 0..2047: barrier regions, 16 groups x 128 ints
// (8 lines x 16 ints each): scan groups 0-7 @0, dec groups 0-7 @1024.
#define OHS  2048                        // harr [2][129][NB][HH]
#define OEO  (OHS + 2*129*NB*HH)         // enc_out [NB][TE][CTXD]
#define OEP  (OEO + NB*TE*CTXD)          // epre [NB][TE][8]
#define ODC  (OEP + NB*TE*8)             // dcat [TD+1][NB][DCW]
#define WSEND (ODC + (TD+1)*NB*DCW)      // ~40.3MB

__device__ __forceinline__ float sigf(float x) { return 1.0f / (1.0f + expf(-x)); }
__device__ __forceinline__ float hsum4(float4 v) { return (v.x + v.y) + (v.z + v.w); }

__device__ __forceinline__ void stg1(float* p, float v) {
  __hip_atomic_store(p, v, __ATOMIC_RELAXED, __HIP_MEMORY_SCOPE_AGENT);
}

__device__ __forceinline__ void fma4(float4& a, const float4 w, const float4 u) {
  a.x = fmaf(w.x, u.x, a.x); a.y = fmaf(w.y, u.y, a.y);
  a.z = fmaf(w.z, u.z, a.z); a.w = fmaf(w.w, u.w, a.w);
}

// Group-local distributed monotonic barrier: 32 participants, arrivals over 8
// cache lines (idx&7), wave 0 polls 8 lines in parallel. All-relaxed
// (agent-acquire = buffer_inv sc1 = L2 nuke, R2 regression). __syncthreads
// drains vmcnt (sc1 stores at L3) before arrival; cross-block data read at
// per-step-fresh addresses only.
__device__ __forceinline__ void gbarG(int* bar, int idx, int target) {
  __syncthreads();
  if (threadIdx.x == 0) {
    __hip_atomic_fetch_add(bar + (idx & 7) * 16, 1,
                           __ATOMIC_RELAXED, __HIP_MEMORY_SCOPE_AGENT);
  }
  if (threadIdx.x < 64) {
    const int ln = threadIdx.x;
    int it = 0;
    while (true) {
      int v = (ln < 8)
        ? __hip_atomic_load(bar + ln * 16, __ATOMIC_RELAXED, __HIP_MEMORY_SCOPE_AGENT)
        : 0;
      v += __shfl_xor(v, 1); v += __shfl_xor(v, 2); v += __shfl_xor(v, 4);
      v = __shfl(v, 0);
      if (v >= target) break;
      __builtin_amdgcn_s_sleep(1);
      if (++it > (1 << 20)) break;  // safety bail: garbage beats hang
    }
  }
  __syncthreads();
}

// ---------------- BiLSTM scan: 256 blocks x 512 thr, persistent ----------------
// group g = bid&7 -> (dir = g>>2, bg = g&3: 8 batches); cg = bid>>3: 16 h-cols
// (64 gate rows r = gate*16+col). Waves: (ks = w&3: 192-k slice, rh = w>>2).
// lane = rq*16+kl: 4 row-quads x 16 k-lanes. Wreg[8][3] = 96 VGPR, loaded once.
// Sync: 32 participants, group-local (batch independence!).
__global__ void __launch_bounds__(512)
scan_kernel(const int* __restrict__ enc_in, const int* __restrict__ lens,
            const float* __restrict__ emb_src,
            const float* __restrict__ Wih_f, const float* __restrict__ Whh_f,
            const float* __restrict__ bih_f, const float* __restrict__ bhh_f,
            const float* __restrict__ Wih_b, const float* __restrict__ Whh_b,
            const float* __restrict__ bih_b, const float* __restrict__ bhh_b,
            float* __restrict__ ws)
{
  const int tid = threadIdx.x, bid = blockIdx.x;
  const int g = bid & 7, cg = bid >> 3;
  const int dir = g >> 2, bg = g & 3;
  int* bar = (int*)ws + g * 128;
  float* harr = ws + OHS;
  float* eo   = ws + OEO;

  asm volatile("buffer_inv sc1" ::: "memory");  // purge stale clean lines (graph replays)

  __shared__ int   tokL[TE][8];        // 4 KB (this bg's 8 batches)
  __shared__ float lds_p[8][4][68];    // 8.7 KB [bb][ks][row(64)+pad]

  for (int i = tid; i < TE * 8; i += 512) {
    int bb = i & 7, s = i >> 3;
    int b = bg * 8 + bb;
    int t = s;
    if (dir) { int L = lens[b]; t = (s < L) ? (L - 1 - s) : s; }
    tokL[s][bb] = enc_in[b * TE + t];
  }
  if (tid < 128) {   // zero own h0 slice: 8 b x 16 cols
    int bb = tid >> 4, col = tid & 15;
    stg1(&harr[((size_t)(dir * 129) * NB + bg * 8 + bb) * HH + cg * 16 + col], 0.0f);
  }

  const int lane = tid & 63, w = tid >> 6;
  const int ks = w & 3, rh = w >> 2;
  const int rq = lane >> 4, kl = lane & 15;
  const int j0 = cg * 16;
  const float* Wih = dir ? Wih_b : Wih_f;
  const float* Whh = dir ? Whh_b : Whh_f;

  // weights once: rows r = rh*32 + rq*8 + ri (r = gate*16+col); kf = (ks*3+p)*16+kl
  float4 Wreg[8][3];
  #pragma unroll
  for (int ri = 0; ri < 8; ++ri) {
    int r = rh * 32 + rq * 8 + ri;
    int o = (r >> 4) * HH + j0 + (r & 15);
    #pragma unroll
    for (int p = 0; p < 3; ++p) {
      int kf = (ks * 3 + p) * 16 + kl;
      Wreg[ri][p] = (kf < 64)
        ? *((const float4*)Wih + (size_t)o * 64 + kf)
        : *((const float4*)Whh + (size_t)o * 128 + (kf - 64));
    }
  }

  // updater role (tid<128): (b_u, col_u); c-state in register
  const int b_u = tid >> 4, col_u = tid & 15;
  const int j_u = j0 + col_u;
  const int bglob = bg * 8 + b_u;
  const int Lu = (tid < 128) ? lens[bglob] : 0;
  float bs0 = 0, bs1 = 0, bs2 = 0, bs3 = 0;
  if (tid < 128) {
    const float* bih = dir ? bih_b : bih_f;
    const float* bhh = dir ? bhh_b : bhh_f;
    bs0 = bih[j_u] + bhh[j_u];
    bs1 = bih[HH + j_u] + bhh[HH + j_u];
    bs2 = bih[2 * HH + j_u] + bhh[2 * HH + j_u];
    bs3 = bih[3 * HH + j_u] + bhh[3 * HH + j_u];
  }
  float cst = 0.0f;

  int tgt = 32;
  gbarG(bar, cg, tgt); tgt += 32;    // h0 + tokL visible

  for (int s = 0; s < TE; ++s) {
    const float4* h4 = (const float4*)(harr + ((size_t)(dir * 129 + s) * NB) * HH);
    #pragma unroll 2
    for (int bb = 0; bb < 8; ++bb) {
      const int b = bg * 8 + bb;
      const int tok = tokL[s][bb];
      const float4* x4 = (const float4*)emb_src + (size_t)tok * 64;
      float4 u[3];
      #pragma unroll
      for (int p = 0; p < 3; ++p) {
        int c = ks * 3 + p;
        u[p] = (c < 4) ? x4[c * 16 + kl]
                       : h4[(size_t)b * 128 + (c - 4) * 16 + kl];
      }
      float sc[8];
      #pragma unroll
      for (int ri = 0; ri < 8; ++ri) {
        float4 a = {0, 0, 0, 0};
        fma4(a, Wreg[ri][0], u[0]);
        fma4(a, Wreg[ri][1], u[1]);
        fma4(a, Wreg[ri][2], u[2]);
        sc[ri] = hsum4(a);
      }
      #pragma unroll
      for (int ri = 0; ri < 8; ++ri) {   // reduce over kl (lane bits 0-3)
        sc[ri] += __shfl_xor(sc[ri], 1);
        sc[ri] += __shfl_xor(sc[ri], 2);
        sc[ri] += __shfl_xor(sc[ri], 4);
        sc[ri] += __shfl_xor(sc[ri], 8);
      }
      if (kl == 0) {
        int r0 = rh * 32 + rq * 8;
        float4 lo = {sc[0], sc[1], sc[2], sc[3]};
        float4 hi = {sc[4], sc[5], sc[6], sc[7]};
        *(float4*)&lds_p[bb][ks][r0]     = lo;
        *(float4*)&lds_p[bb][ks][r0 + 4] = hi;
      }
    }
    __syncthreads();

    if (tid < 128) {
      float gi = bs0, gf = bs1, gg = bs2, go = bs3;
      #pragma unroll
      for (int k2 = 0; k2 < 4; ++k2) {
        gi += lds_p[b_u][k2][col_u];
        gf += lds_p[b_u][k2][16 + col_u];
        gg += lds_p[b_u][k2][32 + col_u];
        go += lds_p[b_u][k2][48 + col_u];
      }
      float c = sigf(gf) * cst + sigf(gi) * tanhf(gg);
      cst = c;
      float h = sigf(go) * tanhf(c);
      stg1(&harr[((size_t)(dir * 129 + s + 1) * NB + bglob) * HH + j_u], h);
      float hm = (s < Lu) ? h : 0.0f;
      int pos = dir ? ((s < Lu) ? (Lu - 1 - s) : s) : s;
      eo[((size_t)bglob * TE + pos) * CTXD + dir * HH + j_u] = hm;  // plain store
    }
    gbarG(bar, cg, tgt); tgt += 32;
  }
}

// ---------------- Decoder: 256 blocks x 512 thr, persistent ----------------
// group g = bid&7: 4 batches (g*4..+3); cg = bid>>3: 16 GRU cols + 32-d ctx slice.
// P2: group-local attn (hpv, scores, softmax, ctx slice) -> sync1 -> P3: GRU
// (48 rows x 1792 k, WD[6][7]=168 VGPR register weights) -> sync2. 32-part sync.
__global__ void __launch_bounds__(512)
dec_kernel(const int* __restrict__ dec_in, const int* __restrict__ lens,
           const float* __restrict__ emb_tgt,
           const float* __restrict__ gWih, const float* __restrict__ gWhh,
           const float* __restrict__ gbih, const float* __restrict__ gbhh,
           const float* __restrict__ attn_W, const float* __restrict__ attn_b,
           const float* __restrict__ attn_v,
           float* __restrict__ ws)
{
  const int tid = threadIdx.x, bid = blockIdx.x;
  const int g = bid & 7, cg = bid >> 3;
  int* bar = (int*)ws + 1024 + g * 128;
  float* eo   = ws + OEO;
  float* ep   = ws + OEP;
  float* dcat = ws + ODC;

  asm volatile("buffer_inv sc1" ::: "memory");

  __shared__ int   tokD[TD][4];
  __shared__ int   lensh[4];
  __shared__ float av8v[8];
  __shared__ float hpv[4][8];
  __shared__ float elds[4][128];
  __shared__ float wlds[4][128];
  __shared__ float mxs[4], invs[4];
  __shared__ float cpart[4][4][32];
  __shared__ float lds_pd[2][4][4][52];

  for (int i = tid; i < TD * 4; i += 512) {
    int bb = i & 3, s = i >> 2;
    tokD[s][bb] = dec_in[(g * 4 + bb) * TD + s];
  }
  if (tid < 8) av8v[tid] = attn_v[tid];
  if (tid < 4) lensh[tid] = lens[g * 4 + tid];

  // group-local pre-phase: ep for own 4 batches (4096 entries) + h0 (2048)
  {
    const int idx = cg * 512 + tid;          // 0..16383
    if (idx < 4 * TE * 8) {
      int a = idx & 7, t = (idx >> 3) & 127, bb = idx >> 10;
      int b = g * 4 + bb;
      float acc = attn_b[a];
      const float* er = &eo[((size_t)b * TE + t) * CTXD];
      for (int d = 0; d < CTXD; d += 4) {
        float4 ev = *(const float4*)&er[d];
        acc = fmaf(ev.x, attn_W[(d + 0) * 8 + a], acc);
        acc = fmaf(ev.y, attn_W[(d + 1) * 8 + a], acc);
        acc = fmaf(ev.z, attn_W[(d + 2) * 8 + a], acc);
        acc = fmaf(ev.w, attn_W[(d + 3) * 8 + a], acc);
      }
      stg1(&ep[((size_t)b * TE + t) * 8 + a], acc);
    }
    if (idx < 4 * HH) {
      int bb = idx >> 9, j = idx & 511;
      stg1(&dcat[(size_t)(g * 4 + bb) * DCW + CTXD + j], 0.0f);
    }
  }

  const int lane = tid & 63, w = tid >> 6;
  const int ks = w & 3, rh = w >> 2;
  const int rq = lane >> 4, kl = lane & 15;

  // GRU register weights: rows r = rh*24 + rq*6 + ri (r = gate*16+col)
  float4 WD[6][7];
  #pragma unroll
  for (int ri = 0; ri < 6; ++ri) {
    int r = rh * 24 + rq * 6 + ri;
    int o = (r >> 4) * HH + cg * 16 + (r & 15);
    #pragma unroll
    for (int p = 0; p < 7; ++p) {
      int kf = (ks * 7 + p) * 16 + kl;
      WD[ri][p] = (kf < 320)
        ? *((const float4*)gWih + (size_t)o * 320 + kf)
        : *((const float4*)gWhh + (size_t)o * 128 + (kf - 320));
    }
  }

  // updater (tid<64): (b_u = tid>>4, col_u = tid&15); h-state in register
  const int b_u = tid >> 4, col_u = tid & 15;
  const int j_u = cg * 16 + col_u;
  float bRi = 0, bRh = 0, bZi = 0, bZh = 0, bNi = 0, bNh = 0;
  if (tid < 64) {
    bRi = gbih[j_u];          bRh = gbhh[j_u];
    bZi = gbih[HH + j_u];     bZh = gbhh[HH + j_u];
    bNi = gbih[2 * HH + j_u]; bNh = gbhh[2 * HH + j_u];
  }
  float hreg = 0.0f;

  int tgt = 32;
  gbarG(bar, cg, tgt); tgt += 32;

  for (int s = 0; s < TD; ++s) {
    // ---- P2: hpv (wave w -> batch w>>1, a-half w&1) ----
    {
      const int bb = w >> 1, b = g * 4 + bb;
      const float4* h4 = (const float4*)(dcat + ((size_t)s * NB + b) * DCW + CTXD);
      float4 ha = h4[lane * 2], hb = h4[lane * 2 + 1];
      #pragma unroll
      for (int i = 0; i < 4; ++i) {
        const int a = (w & 1) * 4 + i;
        const float* wa = attn_W + (size_t)(CTXD + lane * 8) * 8 + a;
        float acc = 0.0f;
        acc = fmaf(ha.x, wa[0],  acc); acc = fmaf(ha.y, wa[8],  acc);
        acc = fmaf(ha.z, wa[16], acc); acc = fmaf(ha.w, wa[24], acc);
        acc = fmaf(hb.x, wa[32], acc); acc = fmaf(hb.y, wa[40], acc);
        acc = fmaf(hb.z, wa[48], acc); acc = fmaf(hb.w, wa[56], acc);
        acc += __shfl_xor(acc, 1);  acc += __shfl_xor(acc, 2);
        acc += __shfl_xor(acc, 4);  acc += __shfl_xor(acc, 8);
        acc += __shfl_xor(acc, 16); acc += __shfl_xor(acc, 32);
        if (lane == 0) hpv[bb][a] = acc;
      }
    }
    __syncthreads();
    // scores: tid = bb*128 + t
    {
      const int bb = tid >> 7, t = tid & 127;
      const int b = g * 4 + bb;
      float evv = -1e9f;
      if (t < lensh[bb]) {
        const float* e8 = &ep[((size_t)b * TE + t) * 8];
        float4 ea = *(const float4*)e8, eb2 = *(const float4*)(e8 + 4);
        evv  = tanhf(ea.x + hpv[bb][0]) * av8v[0];
        evv += tanhf(ea.y + hpv[bb][1]) * av8v[1];
        evv += tanhf(ea.z + hpv[bb][2]) * av8v[2];
        evv += tanhf(ea.w + hpv[bb][3]) * av8v[3];
        evv += tanhf(eb2.x + hpv[bb][4]) * av8v[4];
        evv += tanhf(eb2.y + hpv[bb][5]) * av8v[5];
        evv += tanhf(eb2.z + hpv[bb][6]) * av8v[6];
        evv += tanhf(eb2.w + hpv[bb][7]) * av8v[7];
      }
      elds[bb][t] = evv;
    }
    __syncthreads();
    if (tid < 256) {             // wave w = bb
      const int bb = tid >> 6, i = tid & 63;
      float m = fmaxf(elds[bb][i], elds[bb][i + 64]);
      m = fmaxf(m, __shfl_xor(m, 1));  m = fmaxf(m, __shfl_xor(m, 2));
      m = fmaxf(m, __shfl_xor(m, 4));  m = fmaxf(m, __shfl_xor(m, 8));
      m = fmaxf(m, __shfl_xor(m, 16)); m = fmaxf(m, __shfl_xor(m, 32));
      if (i == 0) mxs[bb] = m;
    }
    __syncthreads();
    {
      const int bb = tid >> 7, t = tid & 127;
      wlds[bb][t] = expf(elds[bb][t] - mxs[bb]);
    }
    __syncthreads();
    if (tid < 256) {
      const int bb = tid >> 6, i = tid & 63;
      float sm = wlds[bb][i] + wlds[bb][i + 64];
      sm += __shfl_xor(sm, 1);  sm += __shfl_xor(sm, 2);
      sm += __shfl_xor(sm, 4);  sm += __shfl_xor(sm, 8);
      sm += __shfl_xor(sm, 16); sm += __shfl_xor(sm, 32);
      if (i == 0) invs[bb] = 1.0f / sm;
    }
    // ctx slice d in [cg*32, cg*32+32): thread = (bb, tq, dq) (dq consecutive)
    {
      const int bb = tid >> 7, r2 = tid & 127, tq = r2 >> 5, dq = r2 & 31;
      const int b = g * 4 + bb;
      float acc = 0.0f;
      const float* ebp = eo + ((size_t)b * TE + tq * 32) * CTXD + cg * 32 + dq;
      #pragma unroll 4
      for (int t = 0; t < 32; ++t)
        acc = fmaf(wlds[bb][tq * 32 + t], ebp[(size_t)t * CTXD], acc);
      cpart[bb][tq][dq] = acc;
    }
    __syncthreads();
    if (tid < 128) {
      const int bb = tid >> 5, dq = tid & 31;
      float c = (cpart[bb][0][dq] + cpart[bb][1][dq] +
                 cpart[bb][2][dq] + cpart[bb][3][dq]) * invs[bb];
      stg1(&dcat[((size_t)s * NB + g * 4 + bb) * DCW + cg * 32 + dq], c);
    }
    gbarG(bar, cg, tgt); tgt += 32;

    // ---- P3: GRU dots (register weights) + update ----
    for (int bb = 0; bb < 4; ++bb) {
      const int b = g * 4 + bb;
      const int tok = tokD[s][bb];
      const float4* x4 = (const float4*)emb_tgt + (size_t)tok * 64;
      const float4* d4 = (const float4*)dcat + ((size_t)s * NB + b) * (DCW / 4);
      float4 u[7];
      #pragma unroll
      for (int p = 0; p < 7; ++p) {
        int c = ks * 7 + p;
        u[p] = (c < 4) ? x4[c * 16 + kl] : d4[(c - 4) * 16 + kl];
      }
      #pragma unroll
      for (int ri = 0; ri < 6; ++ri) {
        float4 aI = {0, 0, 0, 0}, aH = {0, 0, 0, 0};
        #pragma unroll
        for (int p = 0; p < 7; ++p) {
          int c = ks * 7 + p;
          if (c < 20) fma4(aI, WD[ri][p], u[p]);
          else        fma4(aH, WD[ri][p], u[p]);
        }
        float si = hsum4(aI), sh = hsum4(aH);
        si += __shfl_xor(si, 1); sh += __shfl_xor(sh, 1);
        si += __shfl_xor(si, 2); sh += __shfl_xor(sh, 2);
        si += __shfl_xor(si, 4); sh += __shfl_xor(sh, 4);
        si += __shfl_xor(si, 8); sh += __shfl_xor(sh, 8);
        if (kl == 0) {
          int r = rh * 24 + rq * 6 + ri;
          lds_pd[0][bb][ks][r] = si;
          lds_pd[1][bb][ks][r] = sh;
        }
      }
    }
    __syncthreads();
    if (tid < 64) {
      float giR = 0, ghR = 0, giZ = 0, ghZ = 0, giN = 0, ghN = 0;
      #pragma unroll
      for (int k2 = 0; k2 < 4; ++k2) {
        giR += lds_pd[0][b_u][k2][col_u];      ghR += lds_pd[1][b_u][k2][col_u];
        giZ += lds_pd[0][b_u][k2][16 + col_u]; ghZ += lds_pd[1][b_u][k2][16 + col_u];
        giN += lds_pd[0][b_u][k2][32 + col_u]; ghN += lds_pd[1][b_u][k2][32 + col_u];
      }
      float r = sigf(giR + bRi + ghR + bRh);
      float z = sigf(giZ + bZi + ghZ + bZh);
      float n = tanhf(giN + bNi + r * (ghN + bNh));
      float hnew = (1.0f - z) * n + z * hreg;
      hreg = hnew;
      stg1(&dcat[((size_t)(s + 1) * NB + g * 4 + b_u) * DCW + CTXD + j_u], hnew);
    }
    gbarG(bar, cg, tgt); tgt += 32;
  }
}

// ---------------- Classifier: [1024,512] @ clf_W^T [512,32000], relu --------
// 128x128 tile, 256 thr, 8x8 acc/thread.
__global__ void __launch_bounds__(256)
clf_kernel(const float* __restrict__ dcat, const float* __restrict__ W,
           const float* __restrict__ bias, float* __restrict__ out)
{
  asm volatile("buffer_inv sc1" ::: "memory");  // stale-clean-line insurance (replays)
  __shared__ __align__(16) float As[16][132];
  __shared__ __align__(16) float Bs[16][132];
  const int tid = threadIdx.x;
  const int tx = tid & 15, ty = tid >> 4;
  const int n0 = blockIdx.x * 128, m0 = blockIdx.y * 128;
  float acc[8][8] = {};
  const int lr = tid >> 1;            // 0..127
  const int lk = (tid & 1) * 8;       // 0 or 8
  const int r  = m0 + lr;             // r = b*TD + t
  const float* arow = dcat + ((size_t)((r & 31) + 1) * NB + (r >> 5)) * DCW + CTXD;
  const float* brow = W + (size_t)(n0 + lr) * HH;

  for (int kc = 0; kc < HH; kc += 16) {
    float4 av0 = *(const float4*)&arow[kc + lk];
    float4 av1 = *(const float4*)&arow[kc + lk + 4];
    float4 bv0 = *(const float4*)&brow[kc + lk];
    float4 bv1 = *(const float4*)&brow[kc + lk + 4];
    __syncthreads();
    As[lk + 0][lr] = av0.x; As[lk + 1][lr] = av0.y;
    As[lk + 2][lr] = av0.z; As[lk + 3][lr] = av0.w;
    As[lk + 4][lr] = av1.x; As[lk + 5][lr] = av1.y;
    As[lk + 6][lr] = av1.z; As[lk + 7][lr] = av1.w;
    Bs[lk + 0][lr] = bv0.x; Bs[lk + 1][lr] = bv0.y;
    Bs[lk + 2][lr] = bv0.z; Bs[lk + 3][lr] = bv0.w;
    Bs[lk + 4][lr] = bv1.x; Bs[lk + 5][lr] = bv1.y;
    Bs[lk + 6][lr] = bv1.z; Bs[lk + 7][lr] = bv1.w;
    __syncthreads();
    #pragma unroll
    for (int kk = 0; kk < 16; ++kk) {
      float a8[8], b8[8];
      *(float4*)&a8[0] = *(const float4*)&As[kk][ty * 8];
      *(float4*)&a8[4] = *(const float4*)&As[kk][ty * 8 + 4];
      *(float4*)&b8[0] = *(const float4*)&Bs[kk][tx * 8];
      *(float4*)&b8[4] = *(const float4*)&Bs[kk][tx * 8 + 4];
      #pragma unroll
      for (int i = 0; i < 8; ++i)
        #pragma unroll
        for (int j = 0; j < 8; ++j)
          acc[i][j] = fmaf(a8[i], b8[j], acc[i][j]);
    }
  }
  const int col = n0 + tx * 8;
  float bb[8];
  *(float4*)&bb[0] = *(const float4*)&bias[col];
  *(float4*)&bb[4] = *(const float4*)&bias[col + 4];
  #pragma unroll
  for (int i = 0; i < 8; ++i) {
    int row = m0 + ty * 8 + i;
    float4 o0, o1;
    o0.x = fmaxf(acc[i][0] + bb[0], 0.0f); o0.y = fmaxf(acc[i][1] + bb[1], 0.0f);
    o0.z = fmaxf(acc[i][2] + bb[2], 0.0f); o0.w = fmaxf(acc[i][3] + bb[3], 0.0f);
    o1.x = fmaxf(acc[i][4] + bb[4], 0.0f); o1.y = fmaxf(acc[i][5] + bb[5], 0.0f);
    o1.z = fmaxf(acc[i][6] + bb[6], 0.0f); o1.w = fmaxf(acc[i][7] + bb[7], 0.0f);
    *(float4*)&out[(size_t)row * VOC + col]     = o0;
    *(float4*)&out[(size_t)row * VOC + col + 4] = o1;
  }
}

extern "C" void kernel_launch(void* const* d_in, const int* in_sizes, int n_in,
                              void* d_out, int out_size, void* d_ws, size_t ws_size,
                              hipStream_t stream)
{
  if (ws_size < (size_t)WSEND * 4) return;  // visible-failure guard

  const int* enc_in  = (const int*)d_in[0];
  const int* enc_len = (const int*)d_in[1];
  const int* dec_in  = (const int*)d_in[2];
  const float* emb_src = (const float*)d_in[4];
  const float* emb_tgt = (const float*)d_in[5];
  const float* Wih_f = (const float*)d_in[6];
  const float* Whh_f = (const float*)d_in[7];
  const float* bih_f = (const float*)d_in[8];
  const float* bhh_f = (const float*)d_in[9];
  const float* Wih_b = (const float*)d_in[10];
  const float* Whh_b = (const float*)d_in[11];
  const float* bih_b = (const float*)d_in[12];
  const float* bhh_b = (const float*)d_in[13];
  const float* gWih  = (const float*)d_in[14];
  const float* gWhh  = (const float*)d_in[15];
  const float* gbih  = (const float*)d_in[16];
  const float* gbhh  = (const float*)d_in[17];
  const float* attn_W = (const float*)d_in[18];
  const float* attn_b = (const float*)d_in[19];
  const float* attn_v = (const float*)d_in[20];
  const float* clf_W = (const float*)d_in[21];
  const float* clf_b = (const float*)d_in[22];
  float* ws  = (float*)d_ws;
  float* out = (float*)d_out;

  hipMemsetAsync(d_ws, 0, 8192, stream);  // barrier lines (16 groups)
  scan_kernel<<<256, 512, 0, stream>>>(enc_in, enc_len, emb_src,
      Wih_f, Whh_f, bih_f, bhh_f, Wih_b, Whh_b, bih_b, bhh_b, ws);
  dec_kernel<<<256, 512, 0, stream>>>(dec_in, enc_len, emb_tgt,
      gWih, gWhh, gbih, gbhh, attn_W, attn_b, attn_v, ws);
  dim3 cg(VOC / 128, (NB * TD) / 128);
  clf_kernel<<<cg, 256, 0, stream>>>(ws + ODC, clf_W, clf_b, out);
}